// Round 2
// baseline (856.487 us; speedup 1.0000x reference)
//
#include <hip/hip_runtime.h>
#include <math.h>

#define NN 50000
#define NE 600000
#define ET (NN + NE)   // 650000 edges incl. self-loops

// ---------------------------------------------------------------- CSR build
__global__ void k_hist(const int* __restrict__ ei, int* __restrict__ deg) {
    int e = blockIdx.x * blockDim.x + threadIdx.x;
    if (e >= ET) return;
    int d = (e < NE) ? ei[NE + e] : (e - NE);
    atomicAdd(&deg[d], 1);
}

__global__ void k_scan_local(const int* __restrict__ deg, int* __restrict__ tmp,
                             int* __restrict__ csum) {
    __shared__ int wsum[16];
    int i = blockIdx.x * 1024 + threadIdx.x;
    int lane = threadIdx.x & 63, wid = threadIdx.x >> 6;
    int x = (i < NN) ? deg[i] : 0;
    for (int off = 1; off < 64; off <<= 1) {
        int y = __shfl_up(x, off);
        if (lane >= off) x += y;
    }
    if (lane == 63) wsum[wid] = x;
    __syncthreads();
    if (wid == 0) {
        int t = (lane < 16) ? wsum[lane] : 0;
        for (int off = 1; off < 16; off <<= 1) {
            int y = __shfl_up(t, off);
            if (lane >= off) t += y;
        }
        if (lane < 16) wsum[lane] = t;
    }
    __syncthreads();
    if (wid > 0) x += wsum[wid - 1];
    if (i < NN) tmp[i] = x;                       // inclusive within chunk
    if (threadIdx.x == 1023) csum[blockIdx.x] = x; // chunk total
}

__global__ void k_scan_chunks(int* __restrict__ csum, int nchunks) {
    int lane = threadIdx.x;
    int v = (lane < nchunks) ? csum[lane] : 0;
    for (int off = 1; off < 64; off <<= 1) {
        int y = __shfl_up(v, off);
        if (lane >= off) v += y;
    }
    if (lane < nchunks) csum[lane] = v; // inclusive chunk prefix
}

__global__ void k_rowptr(const int* __restrict__ tmp, const int* __restrict__ csum,
                         int* __restrict__ rowptr) {
    int i = blockIdx.x * blockDim.x + threadIdx.x;
    if (i == 0) rowptr[0] = 0;
    if (i < NN) {
        int chunk = i >> 10;
        int off = (chunk > 0) ? csum[chunk - 1] : 0;
        rowptr[i + 1] = tmp[i] + off;
    }
}

__global__ void k_fill(const int* __restrict__ ei, const int* __restrict__ rowptr,
                       int* __restrict__ fill, int* __restrict__ csr) {
    int e = blockIdx.x * blockDim.x + threadIdx.x;
    if (e >= ET) return;
    int s = (e < NE) ? ei[e] : (e - NE);
    int d = (e < NE) ? ei[NE + e] : (e - NE);
    int pos = atomicAdd(&fill[d], 1);
    csr[rowptr[d] + pos] = s;
}

// ---------------------------------------------------------------- GEMM (fp32)
// Tall-skinny: [N,K] x [K,D], 64-row tile per 256-thread block.
template <int K, int D>
__global__ __launch_bounds__(256) void k_gemm(const float* __restrict__ X,
                                              const float* __restrict__ W,
                                              float* __restrict__ Hout, int nrows) {
    __shared__ float Xs[64][K + 1];
    int t = threadIdx.x;
    int row0 = blockIdx.x * 64;
    for (int i = t; i < 64 * K; i += 256) {
        int r = i / K, c = i % K;
        int gr = row0 + r;
        Xs[r][c] = (gr < nrows) ? X[(size_t)gr * K + c] : 0.f;
    }
    __syncthreads();
    constexpr int DC = D / 32;
    int tx = t & 31, ty = t >> 5;
    float acc[8][DC];
#pragma unroll
    for (int r = 0; r < 8; r++)
#pragma unroll
        for (int c = 0; c < DC; c++) acc[r][c] = 0.f;
    for (int k = 0; k < K; k++) {
        float w[DC];
#pragma unroll
        for (int c = 0; c < DC; c++) w[c] = W[k * D + tx + 32 * c];
#pragma unroll
        for (int r = 0; r < 8; r++) {
            float xv = Xs[ty * 8 + r][k];
#pragma unroll
            for (int c = 0; c < DC; c++) acc[r][c] += xv * w[c];
        }
    }
#pragma unroll
    for (int r = 0; r < 8; r++) {
        int gr = row0 + ty * 8 + r;
        if (gr < nrows)
#pragma unroll
            for (int c = 0; c < DC; c++) Hout[(size_t)gr * D + tx + 32 * c] = acc[r][c];
    }
}

// K=64, D=40 (layer 3): one node per 64-thread block; W (10KB) L1-resident.
__global__ void k_gemm_small(const float* __restrict__ X, const float* __restrict__ W,
                             float* __restrict__ Hout) {
    __shared__ float xs[64];
    int n = blockIdx.x, t = threadIdx.x;
    xs[t] = X[n * 64 + t];
    __syncthreads();
    if (t < 40) {
        float acc = 0.f;
#pragma unroll
        for (int k = 0; k < 64; k++) acc += xs[k] * W[k * 40 + t];
        Hout[n * 40 + t] = acc;
    }
}

// ---------------------------------------------------------------- attention scores
template <int H, int C>
__global__ void k_scores(const float* __restrict__ Hb, const float* __restrict__ a_s,
                         const float* __restrict__ a_d, float* __restrict__ S,
                         float* __restrict__ Dv) {
    int t = blockIdx.x * blockDim.x + threadIdx.x;
    if (t >= NN * H) return;
    int n = t / H, h = t % H;
    const float* base = Hb + (size_t)n * (H * C) + h * C;
    float sa = 0.f, da = 0.f;
#pragma unroll
    for (int c = 0; c < C; c++) {
        float v = base[c];
        sa += v * a_s[h * C + c];
        da += v * a_d[h * C + c];
    }
    S[t] = sa;
    Dv[t] = da;
}

// H==1 variant: wave per node, coalesced + shuffle reduce.
template <int C>
__global__ void k_scores1(const float* __restrict__ Hb, const float* __restrict__ a_s,
                          const float* __restrict__ a_d, float* __restrict__ S,
                          float* __restrict__ Dv) {
    int node = (blockIdx.x * blockDim.x + threadIdx.x) >> 6;
    int lane = threadIdx.x & 63;
    if (node >= NN) return;
    float sa = 0.f, da = 0.f;
    for (int c = lane; c < C; c += 64) {
        float v = Hb[(size_t)node * C + c];
        sa += v * a_s[c];
        da += v * a_d[c];
    }
    for (int off = 32; off; off >>= 1) {
        sa += __shfl_xor(sa, off);
        da += __shfl_xor(da, off);
    }
    if (lane == 0) {
        S[node] = sa;
        Dv[node] = da;
    }
}

// ---------------------------------------------------------------- aggregation
// One wave per node. Phase 1: softmax denominator (lane-parallel over edges).
// Phase 2: weighted sum of h[src] rows (lane-parallel over channels).
// Max-free softmax: exp(e)/sum(exp(e)) == exp(e-m)/sum(exp(e-m)); scores are O(1).
template <int H, int C, int D>
__global__ __launch_bounds__(256) void k_aggregate(const float* __restrict__ Hb,
                                                   const float* __restrict__ S,
                                                   const float* __restrict__ Dv,
                                                   const int* __restrict__ rowptr,
                                                   const int* __restrict__ csr,
                                                   float* __restrict__ Out) {
    int node = blockIdx.x * 4 + (threadIdx.x >> 6);
    if (node >= NN) return;
    int lane = threadIdx.x & 63;
    int r0 = rowptr[node], r1 = rowptr[node + 1];
    float dn[H];
#pragma unroll
    for (int h = 0; h < H; h++) dn[h] = Dv[node * H + h];
    // phase 1: denominators
    float den[H];
#pragma unroll
    for (int h = 0; h < H; h++) den[h] = 0.f;
    for (int k = r0 + lane; k < r1; k += 64) {
        int u = csr[k];
#pragma unroll
        for (int h = 0; h < H; h++) {
            float e = S[u * H + h] + dn[h];
            e = (e > 0.f) ? e : 0.2f * e;
            den[h] += __expf(e);
        }
    }
#pragma unroll
    for (int h = 0; h < H; h++) {
        for (int off = 32; off; off >>= 1) den[h] += __shfl_xor(den[h], off);
        den[h] = 1.f / (den[h] + 1e-16f);
    }
    // phase 2: weighted aggregation
    constexpr int NI = (D + 63) / 64;
    float acc[NI];
#pragma unroll
    for (int i = 0; i < NI; i++) acc[i] = 0.f;
    for (int k = r0; k < r1; k++) {
        int u = csr[k];
#pragma unroll
        for (int i = 0; i < NI; i++) {
            int j = lane + 64 * i;
            if ((D & 63) && j >= D) continue;
            int h = (H == 1) ? 0 : (j / C);
            float e = S[u * H + h] + dn[h];
            e = (e > 0.f) ? e : 0.2f * e;
            float w = __expf(e) * den[h];
            acc[i] += Hb[(size_t)u * D + j] * w;
        }
    }
#pragma unroll
    for (int i = 0; i < NI; i++) {
        int j = lane + 64 * i;
        if (j < D) Out[(size_t)node * D + j] = acc[i];
    }
}

// ---------------------------------------------------------------- batchnorm
template <int D>
__global__ void k_bnstats(const float* __restrict__ X, float* __restrict__ colsum,
                          float* __restrict__ colsq) {
    int col = threadIdx.x;
    if (col >= D) return;
    float s = 0.f, q = 0.f;
    for (int r = blockIdx.x; r < NN; r += gridDim.x) {
        float v = X[(size_t)r * D + col];
        s += v;
        q += v * v;
    }
    atomicAdd(&colsum[col], s);
    atomicAdd(&colsq[col], q);
}

// MODE 0: out = elu(bn(x));  MODE 1: out = res + elu(bn(x))
template <int D, int MODE>
__global__ void k_bnapply(const float* __restrict__ X, const float* __restrict__ colsum,
                          const float* __restrict__ colsq, const float* __restrict__ g,
                          const float* __restrict__ be, const float* __restrict__ res,
                          float* __restrict__ Out) {
    int idx = blockIdx.x * blockDim.x + threadIdx.x;
    if (idx >= NN * D) return;
    int col = idx % D;
    float mu = colsum[col] * (1.f / NN);
    float var = colsq[col] * (1.f / NN) - mu * mu;
    float sc = g[col] * rsqrtf(var + 1e-5f);
    float v = sc * (X[idx] - mu) + be[col];
    v = (v > 0.f) ? v : (__expf(v) - 1.f);
    if (MODE == 1) v += res[idx];
    Out[idx] = v;
}

// Layer 3: fused BN + log_softmax over 40 classes; one wave per node.
__global__ void k_bn_logsoftmax(const float* __restrict__ X, const float* __restrict__ colsum,
                                const float* __restrict__ colsq, const float* __restrict__ g,
                                const float* __restrict__ be, float* __restrict__ Out) {
    int node = (blockIdx.x * blockDim.x + threadIdx.x) >> 6;
    int lane = threadIdx.x & 63;
    if (node >= NN) return;
    float bnv = 0.f, v = -1e30f;
    if (lane < 40) {
        float mu = colsum[lane] * (1.f / NN);
        float var = colsq[lane] * (1.f / NN) - mu * mu;
        float sc = g[lane] * rsqrtf(var + 1e-5f);
        bnv = sc * (X[node * 40 + lane] - mu) + be[lane];
        v = bnv;
    }
    float m = v;
    for (int off = 32; off; off >>= 1) m = fmaxf(m, __shfl_xor(m, off));
    float ex = (lane < 40) ? expf(bnv - m) : 0.f;
    for (int off = 32; off; off >>= 1) ex += __shfl_xor(ex, off);
    float lse = m + logf(ex);
    if (lane < 40) Out[node * 40 + lane] = bnv - lse;
}

// ---------------------------------------------------------------- launch
extern "C" void kernel_launch(void* const* d_in, const int* in_sizes, int n_in,
                              void* d_out, int out_size, void* d_ws, size_t ws_size,
                              hipStream_t stream) {
    (void)in_sizes; (void)n_in; (void)out_size; (void)ws_size;
    const float* x   = (const float*)d_in[0];
    const int*   ei  = (const int*)d_in[1];
    const float* W1  = (const float*)d_in[2];
    const float* as1 = (const float*)d_in[3];
    const float* ad1 = (const float*)d_in[4];
    const float* g1  = (const float*)d_in[6];
    const float* be1 = (const float*)d_in[7];
    const float* Wm  = (const float*)d_in[8];
    const float* asm_ = (const float*)d_in[9];
    const float* adm = (const float*)d_in[10];
    const float* gm  = (const float*)d_in[12];
    const float* bem = (const float*)d_in[13];
    const float* W2  = (const float*)d_in[14];
    const float* as2 = (const float*)d_in[15];
    const float* ad2 = (const float*)d_in[16];
    const float* g2  = (const float*)d_in[18];
    const float* be2 = (const float*)d_in[19];
    const float* W3  = (const float*)d_in[20];
    const float* as3 = (const float*)d_in[21];
    const float* ad3 = (const float*)d_in[22];
    const float* g3  = (const float*)d_in[24];
    const float* be3 = (const float*)d_in[25];
    float* out = (float*)d_out;
    // GAT biases b1/bm/b2/b3 cancel inside the immediately-following BN (mean-subtract).

    char* ws = (char*)d_ws;
    size_t off = 0;
    auto alloc = [&](size_t b) {
        void* p = ws + off;
        off = (off + b + 255) & ~(size_t)255;
        return p;
    };
    int* rowptr = (int*)alloc((NN + 1) * 4);
    int* csr    = (int*)alloc((size_t)ET * 4);
    int* deg    = (int*)alloc(NN * 4);   // also reused as fill cursor
    int* tmp    = (int*)alloc(NN * 4);
    int* csum   = (int*)alloc(256 * 4);
    float* A    = (float*)alloc((size_t)NN * 128 * 4);
    float* B    = (float*)alloc((size_t)NN * 128 * 4);
    float* Cb   = (float*)alloc((size_t)NN * 128 * 4);
    float* S    = (float*)alloc((size_t)NN * 8 * 4);
    float* Dv   = (float*)alloc((size_t)NN * 8 * 4);
    float* cs   = (float*)alloc(256 * 4);
    float* cq   = cs + 128;

    const int nchunks = (NN + 1023) / 1024;

    // ---- CSR build (rebuilt every call; ws is re-poisoned by harness)
    hipMemsetAsync(deg, 0, NN * 4, stream);
    k_hist<<<(ET + 255) / 256, 256, 0, stream>>>(ei, deg);
    k_scan_local<<<nchunks, 1024, 0, stream>>>(deg, tmp, csum);
    k_scan_chunks<<<1, 64, 0, stream>>>(csum, nchunks);
    k_rowptr<<<(NN + 255) / 256, 256, 0, stream>>>(tmp, csum, rowptr);
    hipMemsetAsync(deg, 0, NN * 4, stream);
    k_fill<<<(ET + 255) / 256, 256, 0, stream>>>(ei, rowptr, deg, csr);

    const int gemm_blocks = (NN + 63) / 64;
    const int node_wave_blocks = (NN + 3) / 4; // 4 waves of 64 per 256-thread block

    // ---- Layer 1: IN=128 -> H=8 x C=16 (concat, D=128); BN; ELU -> Cb (= residual)
    k_gemm<128, 128><<<gemm_blocks, 256, 0, stream>>>(x, W1, A, NN);
    k_scores<8, 16><<<(NN * 8 + 255) / 256, 256, 0, stream>>>(A, as1, ad1, S, Dv);
    k_aggregate<8, 16, 128><<<node_wave_blocks, 256, 0, stream>>>(A, S, Dv, rowptr, csr, B);
    hipMemsetAsync(cs, 0, 256 * 4, stream);
    k_bnstats<128><<<512, 128, 0, stream>>>(B, cs, cq);
    k_bnapply<128, 0><<<(NN * 128 + 255) / 256, 256, 0, stream>>>(B, cs, cq, g1, be1, nullptr, Cb);

    // ---- Mid layer: 128 -> 128, H=1; BN; ELU; + residual -> A
    k_gemm<128, 128><<<gemm_blocks, 256, 0, stream>>>(Cb, Wm, A, NN);
    k_scores1<128><<<node_wave_blocks, 256, 0, stream>>>(A, asm_, adm, S, Dv);
    k_aggregate<1, 128, 128><<<node_wave_blocks, 256, 0, stream>>>(A, S, Dv, rowptr, csr, B);
    hipMemsetAsync(cs, 0, 256 * 4, stream);
    k_bnstats<128><<<512, 128, 0, stream>>>(B, cs, cq);
    k_bnapply<128, 1><<<(NN * 128 + 255) / 256, 256, 0, stream>>>(B, cs, cq, gm, bem, Cb, A);

    // ---- Layer 2: 128 -> H=4 x C=16 (concat, D=64); BN; ELU -> A (via Cb agg)
    k_gemm<128, 64><<<gemm_blocks, 256, 0, stream>>>(A, W2, B, NN);
    k_scores<4, 16><<<(NN * 4 + 255) / 256, 256, 0, stream>>>(B, as2, ad2, S, Dv);
    k_aggregate<4, 16, 64><<<node_wave_blocks, 256, 0, stream>>>(B, S, Dv, rowptr, csr, Cb);
    hipMemsetAsync(cs, 0, 256 * 4, stream);
    k_bnstats<64><<<512, 64, 0, stream>>>(Cb, cs, cq);
    k_bnapply<64, 0><<<(NN * 64 + 255) / 256, 256, 0, stream>>>(Cb, cs, cq, g2, be2, nullptr, A);

    // ---- Layer 3: 64 -> 40, H=1; BN; log_softmax -> out
    k_gemm_small<<<NN, 64, 0, stream>>>(A, W3, B);
    k_scores1<40><<<node_wave_blocks, 256, 0, stream>>>(B, as3, ad3, S, Dv);
    k_aggregate<1, 40, 40><<<node_wave_blocks, 256, 0, stream>>>(B, S, Dv, rowptr, csr, Cb);
    hipMemsetAsync(cs, 0, 256 * 4, stream);
    k_bnstats<40><<<512, 64, 0, stream>>>(Cb, cs, cq);
    k_bn_logsoftmax<<<node_wave_blocks, 256, 0, stream>>>(Cb, cs, cq, g3, be3, out);
}

// Round 4
// 790.779 us; speedup vs baseline: 1.0831x; 1.0831x over previous
//
#include <hip/hip_runtime.h>
#include <hip/hip_bf16.h>
#include <math.h>

#define NN 50000
#define NE 600000
#define ET (NN + NE)   // 650000 edges incl. self-loops

typedef __hip_bfloat16 bf16;

// ---------------------------------------------------------------- CSR build
__global__ void k_hist(const int* __restrict__ ei, int* __restrict__ deg) {
    int e = blockIdx.x * blockDim.x + threadIdx.x;
    if (e >= ET) return;
    int d = (e < NE) ? ei[NE + e] : (e - NE);
    atomicAdd(&deg[d], 1);
}

__global__ void k_scan_local(const int* __restrict__ deg, int* __restrict__ tmp,
                             int* __restrict__ csum) {
    __shared__ int wsum[16];
    int i = blockIdx.x * 1024 + threadIdx.x;
    int lane = threadIdx.x & 63, wid = threadIdx.x >> 6;
    int x = (i < NN) ? deg[i] : 0;
    for (int off = 1; off < 64; off <<= 1) {
        int y = __shfl_up(x, off);
        if (lane >= off) x += y;
    }
    if (lane == 63) wsum[wid] = x;
    __syncthreads();
    if (wid == 0) {
        int t = (lane < 16) ? wsum[lane] : 0;
        for (int off = 1; off < 16; off <<= 1) {
            int y = __shfl_up(t, off);
            if (lane >= off) t += y;
        }
        if (lane < 16) wsum[lane] = t;
    }
    __syncthreads();
    if (wid > 0) x += wsum[wid - 1];
    if (i < NN) tmp[i] = x;                       // inclusive within chunk
    if (threadIdx.x == 1023) csum[blockIdx.x] = x; // chunk total
}

__global__ void k_scan_chunks(int* __restrict__ csum, int nchunks) {
    int lane = threadIdx.x;
    int v = (lane < nchunks) ? csum[lane] : 0;
    for (int off = 1; off < 64; off <<= 1) {
        int y = __shfl_up(v, off);
        if (lane >= off) v += y;
    }
    if (lane < nchunks) csum[lane] = v; // inclusive chunk prefix
}

__global__ void k_rowptr(const int* __restrict__ tmp, const int* __restrict__ csum,
                         int* __restrict__ rowptr) {
    int i = blockIdx.x * blockDim.x + threadIdx.x;
    if (i == 0) rowptr[0] = 0;
    if (i < NN) {
        int chunk = i >> 10;
        int off = (chunk > 0) ? csum[chunk - 1] : 0;
        rowptr[i + 1] = tmp[i] + off;
    }
}

__global__ void k_fill(const int* __restrict__ ei, const int* __restrict__ rowptr,
                       int* __restrict__ fill, int* __restrict__ csr) {
    int e = blockIdx.x * blockDim.x + threadIdx.x;
    if (e >= ET) return;
    int s = (e < NE) ? ei[e] : (e - NE);
    int d = (e < NE) ? ei[NE + e] : (e - NE);
    int pos = atomicAdd(&fill[d], 1);
    csr[rowptr[d] + pos] = s;
}

// ---------------------------------------------------------------- GEMM (fp32 in, bf16 out)
template <int K, int D>
__global__ __launch_bounds__(256) void k_gemm(const float* __restrict__ X,
                                              const float* __restrict__ W,
                                              bf16* __restrict__ Hout, int nrows) {
    __shared__ float Xs[64][K + 1];
    int t = threadIdx.x;
    int row0 = blockIdx.x * 64;
    for (int i = t; i < 64 * K; i += 256) {
        int r = i / K, c = i % K;
        int gr = row0 + r;
        Xs[r][c] = (gr < nrows) ? X[(size_t)gr * K + c] : 0.f;
    }
    __syncthreads();
    constexpr int DC = D / 32;
    int tx = t & 31, ty = t >> 5;
    float acc[8][DC];
#pragma unroll
    for (int r = 0; r < 8; r++)
#pragma unroll
        for (int c = 0; c < DC; c++) acc[r][c] = 0.f;
    for (int k = 0; k < K; k++) {
        float w[DC];
#pragma unroll
        for (int c = 0; c < DC; c++) w[c] = W[k * D + tx + 32 * c];
#pragma unroll
        for (int r = 0; r < 8; r++) {
            float xv = Xs[ty * 8 + r][k];
#pragma unroll
            for (int c = 0; c < DC; c++) acc[r][c] += xv * w[c];
        }
    }
#pragma unroll
    for (int r = 0; r < 8; r++) {
        int gr = row0 + ty * 8 + r;
        if (gr < nrows)
#pragma unroll
            for (int c = 0; c < DC; c++)
                Hout[(size_t)gr * D + tx + 32 * c] = __float2bfloat16(acc[r][c]);
    }
}

// K=64, D=40 (layer 3): one node per 64-thread block; W (10KB) L1-resident.
__global__ void k_gemm_small(const float* __restrict__ X, const float* __restrict__ W,
                             bf16* __restrict__ Hout) {
    __shared__ float xs[64];
    int n = blockIdx.x, t = threadIdx.x;
    xs[t] = X[n * 64 + t];
    __syncthreads();
    if (t < 40) {
        float acc = 0.f;
#pragma unroll
        for (int k = 0; k < 64; k++) acc += xs[k] * W[k * 40 + t];
        Hout[n * 40 + t] = __float2bfloat16(acc);
    }
}

// ---------------------------------------------------------------- attention scores
template <int H, int C>
__global__ void k_scores(const bf16* __restrict__ Hb, const float* __restrict__ a_s,
                         const float* __restrict__ a_d, float* __restrict__ S,
                         float* __restrict__ Dv) {
    int t = blockIdx.x * blockDim.x + threadIdx.x;
    if (t >= NN * H) return;
    int n = t / H, h = t % H;
    const bf16* base = Hb + (size_t)n * (H * C) + h * C;
    float sa = 0.f, da = 0.f;
#pragma unroll
    for (int c = 0; c < C; c++) {
        float v = __bfloat162float(base[c]);
        sa += v * a_s[h * C + c];
        da += v * a_d[h * C + c];
    }
    S[t] = sa;
    Dv[t] = da;
}

// H==1 variant: wave per node, coalesced + shuffle reduce.
template <int C>
__global__ void k_scores1(const bf16* __restrict__ Hb, const float* __restrict__ a_s,
                          const float* __restrict__ a_d, float* __restrict__ S,
                          float* __restrict__ Dv) {
    int node = (blockIdx.x * blockDim.x + threadIdx.x) >> 6;
    int lane = threadIdx.x & 63;
    if (node >= NN) return;
    float sa = 0.f, da = 0.f;
    for (int c = lane; c < C; c += 64) {
        float v = __bfloat162float(Hb[(size_t)node * C + c]);
        sa += v * a_s[c];
        da += v * a_d[c];
    }
    for (int off = 32; off; off >>= 1) {
        sa += __shfl_xor(sa, off);
        da += __shfl_xor(da, off);
    }
    if (lane == 0) {
        S[node] = sa;
        Dv[node] = da;
    }
}

// ---------------------------------------------------------------- aggregation
// One wave per node. Phase 1: softmax denominator (lane-parallel over edges).
// Phase 2: weighted sum of bf16 h[src] rows; lane j owns column pair (2j, 2j+1),
// head index is lane-constant so the weight chain is one instr sequence per edge.
// For D<=64, two edges are processed per iteration (one per half-wave).
// Max-free softmax: exp(e)/sum(exp(e)) == exp(e-m)/sum(exp(e-m)); scores are O(1).
template <int H, int C, int D>
__global__ __launch_bounds__(256) void k_aggregate(const bf16* __restrict__ Hb,
                                                   const float* __restrict__ S,
                                                   const float* __restrict__ Dv,
                                                   const int* __restrict__ rowptr,
                                                   const int* __restrict__ csr,
                                                   float* __restrict__ Out) {
    int node = blockIdx.x * 4 + (threadIdx.x >> 6);
    if (node >= NN) return;
    int lane = threadIdx.x & 63;
    int r0 = rowptr[node], r1 = rowptr[node + 1];
    float dn[H], den[H];
#pragma unroll
    for (int h = 0; h < H; h++) {
        dn[h] = Dv[node * H + h];
        den[h] = 0.f;
    }
    // phase 1: denominators (lane-parallel over edges)
    for (int k = r0 + lane; k < r1; k += 64) {
        int u = csr[k];
        float sv[H];
        if constexpr (H == 8) {
            float4 s0 = *reinterpret_cast<const float4*>(S + (size_t)u * 8);
            float4 s1 = *reinterpret_cast<const float4*>(S + (size_t)u * 8 + 4);
            sv[0] = s0.x; sv[1] = s0.y; sv[2] = s0.z; sv[3] = s0.w;
            sv[4] = s1.x; sv[5] = s1.y; sv[6] = s1.z; sv[7] = s1.w;
        } else if constexpr (H == 4) {
            float4 s0 = *reinterpret_cast<const float4*>(S + (size_t)u * 4);
            sv[0] = s0.x; sv[1] = s0.y; sv[2] = s0.z; sv[3] = s0.w;
        } else {
            sv[0] = S[u];
        }
#pragma unroll
        for (int h = 0; h < H; h++) {
            float e = sv[h] + dn[h];
            e = fmaxf(e, 0.2f * e);  // leaky_relu
            den[h] += __expf(e);
        }
    }
#pragma unroll
    for (int h = 0; h < H; h++) {
        for (int off = 32; off; off >>= 1) den[h] += __shfl_xor(den[h], off);
        den[h] = 1.f / (den[h] + 1e-16f);
    }
    // phase 2: weighted aggregation over bf16 rows
    constexpr int EPI = (D > 64) ? 1 : 2;  // edges per iteration
    constexpr int LP = 64 / EPI;           // lanes per edge
    int sub = lane / LP;
    int j = lane % LP;          // column pair (2j, 2j+1)
    bool act = (2 * j) < D;
    const int h_l = (2 * j < D) ? (2 * j) / C : 0;  // lane-constant head
    float dninv_l = den[0];
#pragma unroll
    for (int h = 1; h < H; h++) dninv_l = (h_l == h) ? den[h] : dninv_l;
    float dn_l = dn[0];
#pragma unroll
    for (int h = 1; h < H; h++) dn_l = (h_l == h) ? dn[h] : dn_l;

    float ax = 0.f, ay = 0.f;
    for (int k = r0 + sub; k < r1; k += EPI) {
        int u = csr[k];
        float e = S[(size_t)u * H + h_l] + dn_l;
        e = fmaxf(e, 0.2f * e);
        float w = __expf(e) * dninv_l;
        unsigned pv = 0;
        if (act) pv = *reinterpret_cast<const unsigned*>(Hb + (size_t)u * D + 2 * j);
        float lo = __uint_as_float(pv << 16);
        float hi = __uint_as_float(pv & 0xffff0000u);
        ax += w * lo;
        ay += w * hi;
    }
    if (EPI == 2) {
        ax += __shfl_xor(ax, 32);
        ay += __shfl_xor(ay, 32);
    }
    if (act && lane < LP) {
        *reinterpret_cast<float2*>(Out + (size_t)node * D + 2 * j) = make_float2(ax, ay);
    }
}

// ---------------------------------------------------------------- batchnorm
template <int D>
__global__ void k_bnstats(const float* __restrict__ X, float* __restrict__ colsum,
                          float* __restrict__ colsq) {
    int col = threadIdx.x;
    if (col >= D) return;
    float s = 0.f, q = 0.f;
    for (int r = blockIdx.x; r < NN; r += gridDim.x) {
        float v = X[(size_t)r * D + col];
        s += v;
        q += v * v;
    }
    atomicAdd(&colsum[col], s);
    atomicAdd(&colsq[col], q);
}

// MODE 0: out = elu(bn(x));  MODE 1: out = res + elu(bn(x)).  In-place safe.
template <int D, int MODE>
__global__ void k_bnapply(const float* __restrict__ X, const float* __restrict__ colsum,
                          const float* __restrict__ colsq, const float* __restrict__ g,
                          const float* __restrict__ be, const float* __restrict__ res,
                          float* __restrict__ Out) {
    int idx = blockIdx.x * blockDim.x + threadIdx.x;
    if (idx >= NN * D) return;
    int col = idx % D;
    float mu = colsum[col] * (1.f / NN);
    float var = colsq[col] * (1.f / NN) - mu * mu;
    float sc = g[col] * rsqrtf(var + 1e-5f);
    float v = sc * (X[idx] - mu) + be[col];
    v = (v > 0.f) ? v : (__expf(v) - 1.f);
    if (MODE == 1) v += res[idx];
    Out[idx] = v;
}

// Layer 3: fused BN + log_softmax over 40 classes; one wave per node.
__global__ void k_bn_logsoftmax(const float* __restrict__ X, const float* __restrict__ colsum,
                                const float* __restrict__ colsq, const float* __restrict__ g,
                                const float* __restrict__ be, float* __restrict__ Out) {
    int node = (blockIdx.x * blockDim.x + threadIdx.x) >> 6;
    int lane = threadIdx.x & 63;
    if (node >= NN) return;
    float bnv = 0.f, v = -1e30f;
    if (lane < 40) {
        float mu = colsum[lane] * (1.f / NN);
        float var = colsq[lane] * (1.f / NN) - mu * mu;
        float sc = g[lane] * rsqrtf(var + 1e-5f);
        bnv = sc * (X[node * 40 + lane] - mu) + be[lane];
        v = bnv;
    }
    float m = v;
    for (int off = 32; off; off >>= 1) m = fmaxf(m, __shfl_xor(m, off));
    float ex = (lane < 40) ? expf(bnv - m) : 0.f;
    for (int off = 32; off; off >>= 1) ex += __shfl_xor(ex, off);
    float lse = m + logf(ex);
    if (lane < 40) Out[node * 40 + lane] = bnv - lse;
}

// ---------------------------------------------------------------- launch
extern "C" void kernel_launch(void* const* d_in, const int* in_sizes, int n_in,
                              void* d_out, int out_size, void* d_ws, size_t ws_size,
                              hipStream_t stream) {
    (void)in_sizes; (void)n_in; (void)out_size; (void)ws_size;
    const float* x   = (const float*)d_in[0];
    const int*   ei  = (const int*)d_in[1];
    const float* W1  = (const float*)d_in[2];
    const float* as1 = (const float*)d_in[3];
    const float* ad1 = (const float*)d_in[4];
    const float* g1  = (const float*)d_in[6];
    const float* be1 = (const float*)d_in[7];
    const float* Wm  = (const float*)d_in[8];
    const float* asm_ = (const float*)d_in[9];
    const float* adm = (const float*)d_in[10];
    const float* gm  = (const float*)d_in[12];
    const float* bem = (const float*)d_in[13];
    const float* W2  = (const float*)d_in[14];
    const float* as2 = (const float*)d_in[15];
    const float* ad2 = (const float*)d_in[16];
    const float* g2  = (const float*)d_in[18];
    const float* be2 = (const float*)d_in[19];
    const float* W3  = (const float*)d_in[20];
    const float* as3 = (const float*)d_in[21];
    const float* ad3 = (const float*)d_in[22];
    const float* g3  = (const float*)d_in[24];
    const float* be3 = (const float*)d_in[25];
    float* out = (float*)d_out;
    // GAT biases b1/bm/b2/b3 cancel inside the immediately-following BN (mean-subtract).

    char* ws = (char*)d_ws;
    size_t off = 0;
    auto alloc = [&](size_t b) {
        void* p = ws + off;
        off = (off + b + 255) & ~(size_t)255;
        return p;
    };
    int* rowptr = (int*)alloc((NN + 1) * 4);
    int* csr    = (int*)alloc((size_t)ET * 4);
    int* deg    = (int*)alloc(NN * 4);   // also reused as fill cursor
    int* tmp    = (int*)alloc(NN * 4);
    int* csum   = (int*)alloc(256 * 4);
    bf16* Hbf   = (bf16*)alloc((size_t)NN * 128 * 2);
    float* A    = (float*)alloc((size_t)NN * 128 * 4);
    float* B    = (float*)alloc((size_t)NN * 128 * 4);
    float* S    = (float*)alloc((size_t)NN * 8 * 4);
    float* Dv   = (float*)alloc((size_t)NN * 8 * 4);
    float* cs   = (float*)alloc(256 * 4);
    float* cq   = cs + 128;

    const int nchunks = (NN + 1023) / 1024;

    // ---- CSR build (rebuilt every call; ws is re-poisoned by harness)
    hipMemsetAsync(deg, 0, NN * 4, stream);
    k_hist<<<(ET + 255) / 256, 256, 0, stream>>>(ei, deg);
    k_scan_local<<<nchunks, 1024, 0, stream>>>(deg, tmp, csum);
    k_scan_chunks<<<1, 64, 0, stream>>>(csum, nchunks);
    k_rowptr<<<(NN + 255) / 256, 256, 0, stream>>>(tmp, csum, rowptr);
    hipMemsetAsync(deg, 0, NN * 4, stream);
    k_fill<<<(ET + 255) / 256, 256, 0, stream>>>(ei, rowptr, deg, csr);

    const int gemm_blocks = (NN + 63) / 64;
    const int node_wave_blocks = (NN + 3) / 4; // 4 waves of 64 per 256-thread block

    // ---- Layer 1: IN=128 -> H=8 x C=16 (concat, D=128); BN; ELU -> B (= residual)
    k_gemm<128, 128><<<gemm_blocks, 256, 0, stream>>>(x, W1, Hbf, NN);
    k_scores<8, 16><<<(NN * 8 + 255) / 256, 256, 0, stream>>>(Hbf, as1, ad1, S, Dv);
    k_aggregate<8, 16, 128><<<node_wave_blocks, 256, 0, stream>>>(Hbf, S, Dv, rowptr, csr, A);
    hipMemsetAsync(cs, 0, 256 * 4, stream);
    k_bnstats<128><<<512, 128, 0, stream>>>(A, cs, cq);
    k_bnapply<128, 0><<<(NN * 128 + 255) / 256, 256, 0, stream>>>(A, cs, cq, g1, be1, nullptr, B);

    // ---- Mid layer: 128 -> 128, H=1; BN; ELU; + residual(B) -> A (in-place over agg)
    k_gemm<128, 128><<<gemm_blocks, 256, 0, stream>>>(B, Wm, Hbf, NN);
    k_scores1<128><<<node_wave_blocks, 256, 0, stream>>>(Hbf, asm_, adm, S, Dv);
    k_aggregate<1, 128, 128><<<node_wave_blocks, 256, 0, stream>>>(Hbf, S, Dv, rowptr, csr, A);
    hipMemsetAsync(cs, 0, 256 * 4, stream);
    k_bnstats<128><<<512, 128, 0, stream>>>(A, cs, cq);
    k_bnapply<128, 1><<<(NN * 128 + 255) / 256, 256, 0, stream>>>(A, cs, cq, gm, bem, B, A);

    // ---- Layer 2: 128 -> H=4 x C=16 (concat, D=64); BN; ELU -> B (in-place over agg)
    k_gemm<128, 64><<<gemm_blocks, 256, 0, stream>>>(A, W2, Hbf, NN);
    k_scores<4, 16><<<(NN * 4 + 255) / 256, 256, 0, stream>>>(Hbf, as2, ad2, S, Dv);
    k_aggregate<4, 16, 64><<<node_wave_blocks, 256, 0, stream>>>(Hbf, S, Dv, rowptr, csr, B);
    hipMemsetAsync(cs, 0, 256 * 4, stream);
    k_bnstats<64><<<512, 64, 0, stream>>>(B, cs, cq);
    k_bnapply<64, 0><<<(NN * 64 + 255) / 256, 256, 0, stream>>>(B, cs, cq, g2, be2, nullptr, B);

    // ---- Layer 3: 64 -> 40, H=1; BN; log_softmax -> out
    k_gemm_small<<<NN, 64, 0, stream>>>(B, W3, Hbf);
    k_scores1<40><<<node_wave_blocks, 256, 0, stream>>>(Hbf, as3, ad3, S, Dv);
    k_aggregate<1, 40, 40><<<node_wave_blocks, 256, 0, stream>>>(Hbf, S, Dv, rowptr, csr, A);
    hipMemsetAsync(cs, 0, 256 * 4, stream);
    k_bnstats<40><<<512, 64, 0, stream>>>(A, cs, cq);
    k_bn_logsoftmax<<<node_wave_blocks, 256, 0, stream>>>(A, cs, cq, g3, be3, out);
}

// Round 5
// 673.075 us; speedup vs baseline: 1.2725x; 1.1749x over previous
//
#include <hip/hip_runtime.h>
#include <hip/hip_bf16.h>
#include <math.h>

#define NN 50000
#define NE 600000
#define ET (NN + NE)   // 650000 edges incl. self-loops

typedef __hip_bfloat16 bf16;

// ---------------------------------------------------------------- CSR build
__global__ void k_hist(const int* __restrict__ ei, int* __restrict__ deg) {
    int e = blockIdx.x * blockDim.x + threadIdx.x;
    if (e >= ET) return;
    int d = (e < NE) ? ei[NE + e] : (e - NE);
    atomicAdd(&deg[d], 1);
}

__global__ void k_scan_local(const int* __restrict__ deg, int* __restrict__ tmp,
                             int* __restrict__ csum) {
    __shared__ int wsum[16];
    int i = blockIdx.x * 1024 + threadIdx.x;
    int lane = threadIdx.x & 63, wid = threadIdx.x >> 6;
    int x = (i < NN) ? deg[i] : 0;
    for (int off = 1; off < 64; off <<= 1) {
        int y = __shfl_up(x, off);
        if (lane >= off) x += y;
    }
    if (lane == 63) wsum[wid] = x;
    __syncthreads();
    if (wid == 0) {
        int t = (lane < 16) ? wsum[lane] : 0;
        for (int off = 1; off < 16; off <<= 1) {
            int y = __shfl_up(t, off);
            if (lane >= off) t += y;
        }
        if (lane < 16) wsum[lane] = t;
    }
    __syncthreads();
    if (wid > 0) x += wsum[wid - 1];
    if (i < NN) tmp[i] = x;                       // inclusive within chunk
    if (threadIdx.x == 1023) csum[blockIdx.x] = x; // chunk total
}

__global__ void k_scan_chunks(int* __restrict__ csum, int nchunks) {
    int lane = threadIdx.x;
    int v = (lane < nchunks) ? csum[lane] : 0;
    for (int off = 1; off < 64; off <<= 1) {
        int y = __shfl_up(v, off);
        if (lane >= off) v += y;
    }
    if (lane < nchunks) csum[lane] = v; // inclusive chunk prefix
}

__global__ void k_rowptr(const int* __restrict__ tmp, const int* __restrict__ csum,
                         int* __restrict__ rowptr) {
    int i = blockIdx.x * blockDim.x + threadIdx.x;
    if (i == 0) rowptr[0] = 0;
    if (i < NN) {
        int chunk = i >> 10;
        int off = (chunk > 0) ? csum[chunk - 1] : 0;
        rowptr[i + 1] = tmp[i] + off;
    }
}

__global__ void k_fill(const int* __restrict__ ei, const int* __restrict__ rowptr,
                       int* __restrict__ fill, int* __restrict__ csr) {
    int e = blockIdx.x * blockDim.x + threadIdx.x;
    if (e >= ET) return;
    int s = (e < NE) ? ei[e] : (e - NE);
    int d = (e < NE) ? ei[NE + e] : (e - NE);
    int pos = atomicAdd(&fill[d], 1);
    csr[rowptr[d] + pos] = s;
}

// ---------------------------------------------------------------- GEMM (fp32 in, bf16 out)
// FS1: fuse H=1 attention scores (s = h.as, d = h.ad) into the epilogue.
template <int K, int D, bool FS1>
__global__ __launch_bounds__(256) void k_gemm(const float* __restrict__ X,
                                              const float* __restrict__ W,
                                              bf16* __restrict__ Hout, int nrows,
                                              const float* __restrict__ a_s,
                                              const float* __restrict__ a_d,
                                              float* __restrict__ Sout,
                                              float* __restrict__ Dvout) {
    __shared__ float Xs[64][K + 1];
    int t = threadIdx.x;
    int row0 = blockIdx.x * 64;
    for (int i = t; i < 64 * K; i += 256) {
        int r = i / K, c = i % K;
        int gr = row0 + r;
        Xs[r][c] = (gr < nrows) ? X[(size_t)gr * K + c] : 0.f;
    }
    __syncthreads();
    constexpr int DC = D / 32;
    int tx = t & 31, ty = t >> 5;
    float acc[8][DC];
#pragma unroll
    for (int r = 0; r < 8; r++)
#pragma unroll
        for (int c = 0; c < DC; c++) acc[r][c] = 0.f;
    for (int k = 0; k < K; k++) {
        float w[DC];
#pragma unroll
        for (int c = 0; c < DC; c++) w[c] = W[k * D + tx + 32 * c];
#pragma unroll
        for (int r = 0; r < 8; r++) {
            float xv = Xs[ty * 8 + r][k];
#pragma unroll
            for (int c = 0; c < DC; c++) acc[r][c] += xv * w[c];
        }
    }
#pragma unroll
    for (int r = 0; r < 8; r++) {
        int gr = row0 + ty * 8 + r;
        if (gr < nrows)
#pragma unroll
            for (int c = 0; c < DC; c++)
                Hout[(size_t)gr * D + tx + 32 * c] = __float2bfloat16(acc[r][c]);
    }
    if constexpr (FS1) {
        float asv[DC], adv[DC];
#pragma unroll
        for (int c = 0; c < DC; c++) {
            asv[c] = a_s[tx + 32 * c];
            adv[c] = a_d[tx + 32 * c];
        }
#pragma unroll
        for (int r = 0; r < 8; r++) {
            float sa = 0.f, da = 0.f;
#pragma unroll
            for (int c = 0; c < DC; c++) {
                sa += acc[r][c] * asv[c];
                da += acc[r][c] * adv[c];
            }
            // reduce across the 32 threads (tx) sharing this row (xor 1..16 stays in half-wave)
            for (int off = 16; off; off >>= 1) {
                sa += __shfl_xor(sa, off);
                da += __shfl_xor(da, off);
            }
            int gr = row0 + ty * 8 + r;
            if (tx == 0 && gr < nrows) {
                Sout[gr] = sa;
                Dvout[gr] = da;
            }
        }
    }
}

// K=64, D=40 (layer 3): one node per 64-thread block; W (10KB) L1-resident.
// Fuses the H=1 score computation.
__global__ void k_gemm_small(const float* __restrict__ X, const float* __restrict__ W,
                             bf16* __restrict__ Hout, const float* __restrict__ a_s,
                             const float* __restrict__ a_d, float* __restrict__ S,
                             float* __restrict__ Dv) {
    __shared__ float xs[64];
    int n = blockIdx.x, t = threadIdx.x;
    xs[t] = X[n * 64 + t];
    __syncthreads();
    float acc = 0.f;
    if (t < 40) {
#pragma unroll
        for (int k = 0; k < 64; k++) acc += xs[k] * W[k * 40 + t];
        Hout[n * 40 + t] = __float2bfloat16(acc);
    }
    float sa = (t < 40) ? acc * a_s[t] : 0.f;
    float da = (t < 40) ? acc * a_d[t] : 0.f;
    for (int off = 32; off; off >>= 1) {
        sa += __shfl_xor(sa, off);
        da += __shfl_xor(da, off);
    }
    if (t == 0) {
        S[n] = sa;
        Dv[n] = da;
    }
}

// ---------------------------------------------------------------- attention scores (multi-head)
template <int H, int C>
__global__ void k_scores(const bf16* __restrict__ Hb, const float* __restrict__ a_s,
                         const float* __restrict__ a_d, float* __restrict__ S,
                         float* __restrict__ Dv) {
    int t = blockIdx.x * blockDim.x + threadIdx.x;
    if (t >= NN * H) return;
    int n = t / H, h = t % H;
    const bf16* base = Hb + (size_t)n * (H * C) + h * C;
    float sa = 0.f, da = 0.f;
#pragma unroll
    for (int c = 0; c < C; c++) {
        float v = __bfloat162float(base[c]);
        sa += v * a_s[h * C + c];
        da += v * a_d[h * C + c];
    }
    S[t] = sa;
    Dv[t] = da;
}

// ---------------------------------------------------------------- aggregation
// One wave per node.
// Phase 1 (lane-parallel over edges): compute exp(leaky(e)) per edge+head,
//   accumulate softmax denominators, and CACHE the exp values in LDS (<=64 edges).
// Phase 2 (lane-parallel over channels, 4-way unrolled over edges): weighted sum
//   of bf16 h[src] rows; weights come from LDS (no gather, no exp recompute);
//   normalization by 1/den applied once at the end.
// Max-free softmax: exp(e)/sum(exp(e)) == exp(e-m)/sum(exp(e-m)); scores are O(1).
template <int H, int C, int D>
__global__ __launch_bounds__(256) void k_aggregate(const bf16* __restrict__ Hb,
                                                   const float* __restrict__ S,
                                                   const float* __restrict__ Dv,
                                                   const int* __restrict__ rowptr,
                                                   const int* __restrict__ csr,
                                                   float* __restrict__ Out) {
    constexpr int WCAP = 64;
    __shared__ float wl[4][WCAP * H];
    int nl = threadIdx.x >> 6;
    int node = blockIdx.x * 4 + nl;
    if (node >= NN) return;
    int lane = threadIdx.x & 63;
    int r0 = rowptr[node], r1 = rowptr[node + 1];
    int cnt = r1 - r0;
    float dn[H], den[H];
#pragma unroll
    for (int h = 0; h < H; h++) {
        dn[h] = Dv[node * H + h];
        den[h] = 0.f;
    }
    // phase 1: per-edge exp + denominators; cache exp in LDS
    for (int k = lane; k < cnt; k += 64) {
        int u = csr[r0 + k];
        float sv[H];
        if constexpr (H == 8) {
            float4 s0 = *reinterpret_cast<const float4*>(S + (size_t)u * 8);
            float4 s1 = *reinterpret_cast<const float4*>(S + (size_t)u * 8 + 4);
            sv[0] = s0.x; sv[1] = s0.y; sv[2] = s0.z; sv[3] = s0.w;
            sv[4] = s1.x; sv[5] = s1.y; sv[6] = s1.z; sv[7] = s1.w;
        } else if constexpr (H == 4) {
            float4 s0 = *reinterpret_cast<const float4*>(S + (size_t)u * 4);
            sv[0] = s0.x; sv[1] = s0.y; sv[2] = s0.z; sv[3] = s0.w;
        } else {
            sv[0] = S[u];
        }
        float ex[H];
#pragma unroll
        for (int h = 0; h < H; h++) {
            float e = sv[h] + dn[h];
            e = fmaxf(e, 0.2f * e);  // leaky_relu
            ex[h] = __expf(e);
            den[h] += ex[h];
        }
        if (k < WCAP) {
#pragma unroll
            for (int h = 0; h < H; h++) wl[nl][k * H + h] = ex[h];
        }
    }
#pragma unroll
    for (int h = 0; h < H; h++) {
        for (int off = 32; off; off >>= 1) den[h] += __shfl_xor(den[h], off);
        den[h] = 1.f / (den[h] + 1e-16f);
    }
    // no __syncthreads needed: each wave reads only the LDS segment it wrote

    // phase 2: weighted aggregation over bf16 rows
    constexpr int EPI = (D > 64) ? 1 : 2;  // edges per iteration
    constexpr int LP = 64 / EPI;           // lanes per edge
    int sub = lane / LP;
    int j = lane % LP;          // column pair (2j, 2j+1)
    bool act = (2 * j) < D;
    const int h_l = act ? (2 * j) / C : 0;  // lane-constant head
    float dninv_l = den[0], dn_l = dn[0];
#pragma unroll
    for (int h = 1; h < H; h++) {
        dninv_l = (h_l == h) ? den[h] : dninv_l;
        dn_l = (h_l == h) ? dn[h] : dn_l;
    }
    const float* wlp = &wl[nl][0];
    auto wof = [&](int idx, int u) -> float {
        if (idx < WCAP) return wlp[idx * H + h_l];  // cached (normal path)
        float e = S[(size_t)u * H + h_l] + dn_l;    // overflow fallback (deg > 64)
        e = fmaxf(e, 0.2f * e);
        return __expf(e);
    };
    float ax = 0.f, ay = 0.f;
    int k = sub;
    for (; k + 3 * EPI < cnt; k += 4 * EPI) {
        int u0 = csr[r0 + k];
        int u1 = csr[r0 + k + EPI];
        int u2 = csr[r0 + k + 2 * EPI];
        int u3 = csr[r0 + k + 3 * EPI];
        unsigned p0 = 0, p1 = 0, p2 = 0, p3 = 0;
        if (act) {
            p0 = *reinterpret_cast<const unsigned*>(Hb + (size_t)u0 * D + 2 * j);
            p1 = *reinterpret_cast<const unsigned*>(Hb + (size_t)u1 * D + 2 * j);
            p2 = *reinterpret_cast<const unsigned*>(Hb + (size_t)u2 * D + 2 * j);
            p3 = *reinterpret_cast<const unsigned*>(Hb + (size_t)u3 * D + 2 * j);
        }
        float w0 = wof(k, u0), w1 = wof(k + EPI, u1);
        float w2 = wof(k + 2 * EPI, u2), w3 = wof(k + 3 * EPI, u3);
        ax += w0 * __uint_as_float(p0 << 16) + w1 * __uint_as_float(p1 << 16) +
              w2 * __uint_as_float(p2 << 16) + w3 * __uint_as_float(p3 << 16);
        ay += w0 * __uint_as_float(p0 & 0xffff0000u) + w1 * __uint_as_float(p1 & 0xffff0000u) +
              w2 * __uint_as_float(p2 & 0xffff0000u) + w3 * __uint_as_float(p3 & 0xffff0000u);
    }
    for (; k < cnt; k += EPI) {
        int u = csr[r0 + k];
        unsigned pv = 0;
        if (act) pv = *reinterpret_cast<const unsigned*>(Hb + (size_t)u * D + 2 * j);
        float w = wof(k, u);
        ax += w * __uint_as_float(pv << 16);
        ay += w * __uint_as_float(pv & 0xffff0000u);
    }
    if (EPI == 2) {
        ax += __shfl_xor(ax, 32);
        ay += __shfl_xor(ay, 32);
    }
    if (act && lane < LP) {
        *reinterpret_cast<float2*>(Out + (size_t)node * D + 2 * j) =
            make_float2(ax * dninv_l, ay * dninv_l);
    }
}

// ---------------------------------------------------------------- batchnorm
template <int D>
__global__ void k_bnstats(const float* __restrict__ X, float* __restrict__ colsum,
                          float* __restrict__ colsq) {
    int col = threadIdx.x;
    if (col >= D) return;
    float s = 0.f, q = 0.f;
    for (int r = blockIdx.x; r < NN; r += gridDim.x) {
        float v = X[(size_t)r * D + col];
        s += v;
        q += v * v;
    }
    atomicAdd(&colsum[col], s);
    atomicAdd(&colsq[col], q);
}

// MODE 0: out = elu(bn(x));  MODE 1: out = res + elu(bn(x)).  In-place safe.
template <int D, int MODE>
__global__ void k_bnapply(const float* __restrict__ X, const float* __restrict__ colsum,
                          const float* __restrict__ colsq, const float* __restrict__ g,
                          const float* __restrict__ be, const float* __restrict__ res,
                          float* __restrict__ Out) {
    int idx = blockIdx.x * blockDim.x + threadIdx.x;
    if (idx >= NN * D) return;
    int col = idx % D;
    float mu = colsum[col] * (1.f / NN);
    float var = colsq[col] * (1.f / NN) - mu * mu;
    float sc = g[col] * rsqrtf(var + 1e-5f);
    float v = sc * (X[idx] - mu) + be[col];
    v = (v > 0.f) ? v : (__expf(v) - 1.f);
    if (MODE == 1) v += res[idx];
    Out[idx] = v;
}

// Layer 3: fused BN + log_softmax over 40 classes; one wave per node.
__global__ void k_bn_logsoftmax(const float* __restrict__ X, const float* __restrict__ colsum,
                                const float* __restrict__ colsq, const float* __restrict__ g,
                                const float* __restrict__ be, float* __restrict__ Out) {
    int node = (blockIdx.x * blockDim.x + threadIdx.x) >> 6;
    int lane = threadIdx.x & 63;
    if (node >= NN) return;
    float bnv = 0.f, v = -1e30f;
    if (lane < 40) {
        float mu = colsum[lane] * (1.f / NN);
        float var = colsq[lane] * (1.f / NN) - mu * mu;
        float sc = g[lane] * rsqrtf(var + 1e-5f);
        bnv = sc * (X[node * 40 + lane] - mu) + be[lane];
        v = bnv;
    }
    float m = v;
    for (int off = 32; off; off >>= 1) m = fmaxf(m, __shfl_xor(m, off));
    float ex = (lane < 40) ? expf(bnv - m) : 0.f;
    for (int off = 32; off; off >>= 1) ex += __shfl_xor(ex, off);
    float lse = m + logf(ex);
    if (lane < 40) Out[node * 40 + lane] = bnv - lse;
}

// ---------------------------------------------------------------- launch
extern "C" void kernel_launch(void* const* d_in, const int* in_sizes, int n_in,
                              void* d_out, int out_size, void* d_ws, size_t ws_size,
                              hipStream_t stream) {
    (void)in_sizes; (void)n_in; (void)out_size; (void)ws_size;
    const float* x   = (const float*)d_in[0];
    const int*   ei  = (const int*)d_in[1];
    const float* W1  = (const float*)d_in[2];
    const float* as1 = (const float*)d_in[3];
    const float* ad1 = (const float*)d_in[4];
    const float* g1  = (const float*)d_in[6];
    const float* be1 = (const float*)d_in[7];
    const float* Wm  = (const float*)d_in[8];
    const float* asm_ = (const float*)d_in[9];
    const float* adm = (const float*)d_in[10];
    const float* gm  = (const float*)d_in[12];
    const float* bem = (const float*)d_in[13];
    const float* W2  = (const float*)d_in[14];
    const float* as2 = (const float*)d_in[15];
    const float* ad2 = (const float*)d_in[16];
    const float* g2  = (const float*)d_in[18];
    const float* be2 = (const float*)d_in[19];
    const float* W3  = (const float*)d_in[20];
    const float* as3 = (const float*)d_in[21];
    const float* ad3 = (const float*)d_in[22];
    const float* g3  = (const float*)d_in[24];
    const float* be3 = (const float*)d_in[25];
    float* out = (float*)d_out;
    // GAT biases b1/bm/b2/b3 cancel inside the immediately-following BN (mean-subtract).

    char* ws = (char*)d_ws;
    size_t off = 0;
    auto alloc = [&](size_t b) {
        void* p = ws + off;
        off = (off + b + 255) & ~(size_t)255;
        return p;
    };
    int* rowptr = (int*)alloc((NN + 1) * 4);
    int* csr    = (int*)alloc((size_t)ET * 4);
    int* deg    = (int*)alloc(NN * 4);   // also reused as fill cursor
    int* tmp    = (int*)alloc(NN * 4);
    int* csum   = (int*)alloc(256 * 4);
    bf16* Hbf   = (bf16*)alloc((size_t)NN * 128 * 2);
    float* A    = (float*)alloc((size_t)NN * 128 * 4);
    float* B    = (float*)alloc((size_t)NN * 128 * 4);
    float* S    = (float*)alloc((size_t)NN * 8 * 4);
    float* Dv   = (float*)alloc((size_t)NN * 8 * 4);
    float* cs   = (float*)alloc(256 * 4);
    float* cq   = cs + 128;

    const int nchunks = (NN + 1023) / 1024;

    // ---- CSR build (rebuilt every call; ws is re-poisoned by harness)
    hipMemsetAsync(deg, 0, NN * 4, stream);
    k_hist<<<(ET + 255) / 256, 256, 0, stream>>>(ei, deg);
    k_scan_local<<<nchunks, 1024, 0, stream>>>(deg, tmp, csum);
    k_scan_chunks<<<1, 64, 0, stream>>>(csum, nchunks);
    k_rowptr<<<(NN + 255) / 256, 256, 0, stream>>>(tmp, csum, rowptr);
    hipMemsetAsync(deg, 0, NN * 4, stream);
    k_fill<<<(ET + 255) / 256, 256, 0, stream>>>(ei, rowptr, deg, csr);

    const int gemm_blocks = (NN + 63) / 64;
    const int node_wave_blocks = (NN + 3) / 4; // 4 waves of 64 per 256-thread block

    // ---- Layer 1: IN=128 -> H=8 x C=16 (concat, D=128); BN; ELU -> B (= residual)
    k_gemm<128, 128, false><<<gemm_blocks, 256, 0, stream>>>(x, W1, Hbf, NN, nullptr, nullptr, nullptr, nullptr);
    k_scores<8, 16><<<(NN * 8 + 255) / 256, 256, 0, stream>>>(Hbf, as1, ad1, S, Dv);
    k_aggregate<8, 16, 128><<<node_wave_blocks, 256, 0, stream>>>(Hbf, S, Dv, rowptr, csr, A);
    hipMemsetAsync(cs, 0, 256 * 4, stream);
    k_bnstats<128><<<512, 128, 0, stream>>>(A, cs, cq);
    k_bnapply<128, 0><<<(NN * 128 + 255) / 256, 256, 0, stream>>>(A, cs, cq, g1, be1, nullptr, B);

    // ---- Mid layer: 128 -> 128, H=1 (scores fused into GEMM); BN; ELU; + residual(B) -> A
    k_gemm<128, 128, true><<<gemm_blocks, 256, 0, stream>>>(B, Wm, Hbf, NN, asm_, adm, S, Dv);
    k_aggregate<1, 128, 128><<<node_wave_blocks, 256, 0, stream>>>(Hbf, S, Dv, rowptr, csr, A);
    hipMemsetAsync(cs, 0, 256 * 4, stream);
    k_bnstats<128><<<512, 128, 0, stream>>>(A, cs, cq);
    k_bnapply<128, 1><<<(NN * 128 + 255) / 256, 256, 0, stream>>>(A, cs, cq, gm, bem, B, A);

    // ---- Layer 2: 128 -> H=4 x C=16 (concat, D=64); BN; ELU -> B (in-place over agg)
    k_gemm<128, 64, false><<<gemm_blocks, 256, 0, stream>>>(A, W2, Hbf, NN, nullptr, nullptr, nullptr, nullptr);
    k_scores<4, 16><<<(NN * 4 + 255) / 256, 256, 0, stream>>>(Hbf, as2, ad2, S, Dv);
    k_aggregate<4, 16, 64><<<node_wave_blocks, 256, 0, stream>>>(Hbf, S, Dv, rowptr, csr, B);
    hipMemsetAsync(cs, 0, 256 * 4, stream);
    k_bnstats<64><<<512, 64, 0, stream>>>(B, cs, cq);
    k_bnapply<64, 0><<<(NN * 64 + 255) / 256, 256, 0, stream>>>(B, cs, cq, g2, be2, nullptr, B);

    // ---- Layer 3: 64 -> 40, H=1 (scores fused into GEMM); BN; log_softmax -> out
    k_gemm_small<<<NN, 64, 0, stream>>>(B, W3, Hbf, as3, ad3, S, Dv);
    k_aggregate<1, 40, 40><<<node_wave_blocks, 256, 0, stream>>>(Hbf, S, Dv, rowptr, csr, A);
    hipMemsetAsync(cs, 0, 256 * 4, stream);
    k_bnstats<40><<<512, 64, 0, stream>>>(A, cs, cq);
    k_bn_logsoftmax<<<node_wave_blocks, 256, 0, stream>>>(A, cs, cq, g3, be3, out);
}

// Round 7
// 624.886 us; speedup vs baseline: 1.3706x; 1.0771x over previous
//
#include <hip/hip_runtime.h>
#include <hip/hip_bf16.h>
#include <math.h>

#define NN 50000
#define NE 600000
#define ET (NN + NE)   // 650000 edges incl. self-loops

typedef __hip_bfloat16 bf16;
typedef __attribute__((ext_vector_type(8))) short bf16x8;
typedef __attribute__((ext_vector_type(4))) float f32x4;

static __device__ inline unsigned short f2bf(float f) {
    union { __hip_bfloat16 h; unsigned short u; } v;
    v.h = __float2bfloat16(f);
    return v.u;
}

// ---------------------------------------------------------------- CSR build
__global__ void k_hist(const int* __restrict__ ei, int* __restrict__ deg) {
    int e = blockIdx.x * blockDim.x + threadIdx.x;
    if (e >= ET) return;
    int d = (e < NE) ? ei[NE + e] : (e - NE);
    atomicAdd(&deg[d], 1);
}

__global__ void k_scan_local(const int* __restrict__ deg, int* __restrict__ tmp,
                             int* __restrict__ csum) {
    __shared__ int wsum[16];
    int i = blockIdx.x * 1024 + threadIdx.x;
    int lane = threadIdx.x & 63, wid = threadIdx.x >> 6;
    int x = (i < NN) ? deg[i] : 0;
    for (int off = 1; off < 64; off <<= 1) {
        int y = __shfl_up(x, off);
        if (lane >= off) x += y;
    }
    if (lane == 63) wsum[wid] = x;
    __syncthreads();
    if (wid == 0) {
        int t = (lane < 16) ? wsum[lane] : 0;
        for (int off = 1; off < 16; off <<= 1) {
            int y = __shfl_up(t, off);
            if (lane >= off) t += y;
        }
        if (lane < 16) wsum[lane] = t;
    }
    __syncthreads();
    if (wid > 0) x += wsum[wid - 1];
    if (i < NN) tmp[i] = x;                       // inclusive within chunk
    if (threadIdx.x == 1023) csum[blockIdx.x] = x; // chunk total
}

__global__ void k_scan_chunks(int* __restrict__ csum, int nchunks) {
    int lane = threadIdx.x;
    int v = (lane < nchunks) ? csum[lane] : 0;
    for (int off = 1; off < 64; off <<= 1) {
        int y = __shfl_up(v, off);
        if (lane >= off) v += y;
    }
    if (lane < nchunks) csum[lane] = v; // inclusive chunk prefix
}

__global__ void k_rowptr(const int* __restrict__ tmp, const int* __restrict__ csum,
                         int* __restrict__ rowptr) {
    int i = blockIdx.x * blockDim.x + threadIdx.x;
    if (i == 0) rowptr[0] = 0;
    if (i < NN) {
        int chunk = i >> 10;
        int off = (chunk > 0) ? csum[chunk - 1] : 0;
        rowptr[i + 1] = tmp[i] + off;
    }
}

__global__ void k_fill(const int* __restrict__ ei, const int* __restrict__ rowptr,
                       int* __restrict__ fill, int* __restrict__ csr) {
    int e = blockIdx.x * blockDim.x + threadIdx.x;
    if (e >= ET) return;
    int s = (e < NE) ? ei[e] : (e - NE);
    int d = (e < NE) ? ei[NE + e] : (e - NE);
    int pos = atomicAdd(&fill[d], 1);
    csr[rowptr[d] + pos] = s;
}

// ---------------------------------------------------------------- weight transpose+convert
// W [K][D] fp32 -> WT [D][K] bf16 (tiny; L1-resident thereafter)
template <int K, int D>
__global__ void k_wconv(const float* __restrict__ W, short* __restrict__ WT) {
    int idx = blockIdx.x * 256 + threadIdx.x;
    if (idx >= K * D) return;
    int d = idx / K, k = idx % K;
    WT[idx] = (short)f2bf(W[k * D + d]);
}

// ---------------------------------------------------------------- MFMA GEMM (K=128 fixed)
// One wave per 16-row tile; grid = NN/16 = 3125 (exact). No LDS, no barrier.
// A-frag: X row (lane&15), k = (lane>>4)*8+j, fp32 -> bf16 in-register.
// B-frag: WT[n*16+(lane&15)][k0+(lane>>4)*8+j] (16B global load, L1-hit).
// C/D: row=(lane>>4)*4+reg, col=lane&15 (m89-verified).
// HF: fused attention heads. For C=16 layers head == col-tile index n.
template <int D, int HF>
__global__ __launch_bounds__(64) void k_gemm_mfma(const float* __restrict__ X,
                                                  const short* __restrict__ WT,
                                                  bf16* __restrict__ Hout,
                                                  const float* __restrict__ a_s,
                                                  const float* __restrict__ a_d,
                                                  float* __restrict__ S,
                                                  float* __restrict__ Dv) {
    constexpr int K = 128;
    constexpr int NT = D / 16;
    int lane = threadIdx.x;
    int rb = blockIdx.x * 16;
    int m = lane & 15, kg = lane >> 4;

    f32x4 acc[NT];
#pragma unroll
    for (int n = 0; n < NT; n++) acc[n] = (f32x4){0.f, 0.f, 0.f, 0.f};

    const float* xp = X + (size_t)(rb + m) * K + kg * 8;
#pragma unroll
    for (int k0 = 0; k0 < K; k0 += 32) {
        float4 f0 = *reinterpret_cast<const float4*>(xp + k0);
        float4 f1 = *reinterpret_cast<const float4*>(xp + k0 + 4);
        bf16x8 a;
        a[0] = (short)f2bf(f0.x); a[1] = (short)f2bf(f0.y);
        a[2] = (short)f2bf(f0.z); a[3] = (short)f2bf(f0.w);
        a[4] = (short)f2bf(f1.x); a[5] = (short)f2bf(f1.y);
        a[6] = (short)f2bf(f1.z); a[7] = (short)f2bf(f1.w);
#pragma unroll
        for (int n = 0; n < NT; n++) {
            bf16x8 b = *reinterpret_cast<const bf16x8*>(WT + (size_t)(n * 16 + m) * K + k0 + kg * 8);
            acc[n] = __builtin_amdgcn_mfma_f32_16x16x32_bf16(a, b, acc[n], 0, 0, 0);
        }
    }

    float asv[NT], adv[NT];
#pragma unroll
    for (int n = 0; n < NT; n++) {
        asv[n] = a_s[n * 16 + m];
        adv[n] = a_d[n * 16 + m];
    }
#pragma unroll
    for (int r = 0; r < 4; r++) {
        int row = rb + kg * 4 + r;
#pragma unroll
        for (int n = 0; n < NT; n++)
            Hout[(size_t)row * D + n * 16 + m] = __float2bfloat16(acc[n][r]);
        if constexpr (HF == 1) {
            float sa = 0.f, da = 0.f;
#pragma unroll
            for (int n = 0; n < NT; n++) {
                sa += acc[n][r] * asv[n];
                da += acc[n][r] * adv[n];
            }
            for (int off = 1; off < 16; off <<= 1) {
                sa += __shfl_xor(sa, off);
                da += __shfl_xor(da, off);
            }
            if (m == 0) { S[row] = sa; Dv[row] = da; }
        } else {
            // C == 16: head index == col-tile index n
#pragma unroll
            for (int n = 0; n < NT; n++) {
                float sa = acc[n][r] * asv[n];
                float da = acc[n][r] * adv[n];
                for (int off = 1; off < 16; off <<= 1) {
                    sa += __shfl_xor(sa, off);
                    da += __shfl_xor(da, off);
                }
                if (m == 0) { S[row * HF + n] = sa; Dv[row * HF + n] = da; }
            }
        }
    }
}

// K=64, D=40 (layer 3): one node per 64-thread block; W (10KB) L1-resident.
// Fuses the H=1 score computation.
__global__ void k_gemm_small(const float* __restrict__ X, const float* __restrict__ W,
                             bf16* __restrict__ Hout, const float* __restrict__ a_s,
                             const float* __restrict__ a_d, float* __restrict__ S,
                             float* __restrict__ Dv) {
    __shared__ float xs[64];
    int n = blockIdx.x, t = threadIdx.x;
    xs[t] = X[n * 64 + t];
    __syncthreads();
    float acc = 0.f;
    if (t < 40) {
#pragma unroll
        for (int k = 0; k < 64; k++) acc += xs[k] * W[k * 40 + t];
        Hout[n * 40 + t] = __float2bfloat16(acc);
    }
    float sa = (t < 40) ? acc * a_s[t] : 0.f;
    float da = (t < 40) ? acc * a_d[t] : 0.f;
    for (int off = 32; off; off >>= 1) {
        sa += __shfl_xor(sa, off);
        da += __shfl_xor(da, off);
    }
    if (t == 0) {
        S[n] = sa;
        Dv[n] = da;
    }
}

// ---------------------------------------------------------------- aggregation
// One wave per node; phase-1 LDS weight cache; phase-2 4-way unrolled gather.
template <int H, int C, int D>
__global__ __launch_bounds__(256) void k_aggregate(const bf16* __restrict__ Hb,
                                                   const float* __restrict__ S,
                                                   const float* __restrict__ Dv,
                                                   const int* __restrict__ rowptr,
                                                   const int* __restrict__ csr,
                                                   float* __restrict__ Out) {
    constexpr int WCAP = 64;
    __shared__ float wl[4][WCAP * H];
    int nl = threadIdx.x >> 6;
    int node = blockIdx.x * 4 + nl;
    if (node >= NN) return;
    int lane = threadIdx.x & 63;
    int r0 = rowptr[node], r1 = rowptr[node + 1];
    int cnt = r1 - r0;
    float dn[H], den[H];
#pragma unroll
    for (int h = 0; h < H; h++) {
        dn[h] = Dv[node * H + h];
        den[h] = 0.f;
    }
    // phase 1: per-edge exp + denominators; cache exp in LDS
    for (int k = lane; k < cnt; k += 64) {
        int u = csr[r0 + k];
        float sv[H];
        if constexpr (H == 8) {
            float4 s0 = *reinterpret_cast<const float4*>(S + (size_t)u * 8);
            float4 s1 = *reinterpret_cast<const float4*>(S + (size_t)u * 8 + 4);
            sv[0] = s0.x; sv[1] = s0.y; sv[2] = s0.z; sv[3] = s0.w;
            sv[4] = s1.x; sv[5] = s1.y; sv[6] = s1.z; sv[7] = s1.w;
        } else if constexpr (H == 4) {
            float4 s0 = *reinterpret_cast<const float4*>(S + (size_t)u * 4);
            sv[0] = s0.x; sv[1] = s0.y; sv[2] = s0.z; sv[3] = s0.w;
        } else {
            sv[0] = S[u];
        }
        float ex[H];
#pragma unroll
        for (int h = 0; h < H; h++) {
            float e = sv[h] + dn[h];
            e = fmaxf(e, 0.2f * e);  // leaky_relu
            ex[h] = __expf(e);
            den[h] += ex[h];
        }
        if (k < WCAP) {
#pragma unroll
            for (int h = 0; h < H; h++) wl[nl][k * H + h] = ex[h];
        }
    }
#pragma unroll
    for (int h = 0; h < H; h++) {
        for (int off = 32; off; off >>= 1) den[h] += __shfl_xor(den[h], off);
        den[h] = 1.f / (den[h] + 1e-16f);
    }
    // no __syncthreads needed: each wave reads only the LDS segment it wrote

    // phase 2: weighted aggregation over bf16 rows
    constexpr int EPI = (D > 64) ? 1 : 2;  // edges per iteration
    constexpr int LP = 64 / EPI;           // lanes per edge
    int sub = lane / LP;
    int j = lane % LP;          // column pair (2j, 2j+1)
    bool act = (2 * j) < D;
    const int h_l = act ? (2 * j) / C : 0;  // lane-constant head
    float dninv_l = den[0], dn_l = dn[0];
#pragma unroll
    for (int h = 1; h < H; h++) {
        dninv_l = (h_l == h) ? den[h] : dninv_l;
        dn_l = (h_l == h) ? dn[h] : dn_l;
    }
    const float* wlp = &wl[nl][0];
    auto wof = [&](int idx, int u) -> float {
        if (idx < WCAP) return wlp[idx * H + h_l];  // cached (normal path)
        float e = S[(size_t)u * H + h_l] + dn_l;    // overflow fallback (deg > 64)
        e = fmaxf(e, 0.2f * e);
        return __expf(e);
    };
    float ax = 0.f, ay = 0.f;
    int k = sub;
    for (; k + 3 * EPI < cnt; k += 4 * EPI) {
        int u0 = csr[r0 + k];
        int u1 = csr[r0 + k + EPI];
        int u2 = csr[r0 + k + 2 * EPI];
        int u3 = csr[r0 + k + 3 * EPI];
        unsigned p0 = 0, p1 = 0, p2 = 0, p3 = 0;
        if (act) {
            p0 = *reinterpret_cast<const unsigned*>(Hb + (size_t)u0 * D + 2 * j);
            p1 = *reinterpret_cast<const unsigned*>(Hb + (size_t)u1 * D + 2 * j);
            p2 = *reinterpret_cast<const unsigned*>(Hb + (size_t)u2 * D + 2 * j);
            p3 = *reinterpret_cast<const unsigned*>(Hb + (size_t)u3 * D + 2 * j);
        }
        float w0 = wof(k, u0), w1 = wof(k + EPI, u1);
        float w2 = wof(k + 2 * EPI, u2), w3 = wof(k + 3 * EPI, u3);
        ax += w0 * __uint_as_float(p0 << 16) + w1 * __uint_as_float(p1 << 16) +
              w2 * __uint_as_float(p2 << 16) + w3 * __uint_as_float(p3 << 16);
        ay += w0 * __uint_as_float(p0 & 0xffff0000u) + w1 * __uint_as_float(p1 & 0xffff0000u) +
              w2 * __uint_as_float(p2 & 0xffff0000u) + w3 * __uint_as_float(p3 & 0xffff0000u);
    }
    for (; k < cnt; k += EPI) {
        int u = csr[r0 + k];
        unsigned pv = 0;
        if (act) pv = *reinterpret_cast<const unsigned*>(Hb + (size_t)u * D + 2 * j);
        float w = wof(k, u);
        ax += w * __uint_as_float(pv << 16);
        ay += w * __uint_as_float(pv & 0xffff0000u);
    }
    if (EPI == 2) {
        ax += __shfl_xor(ax, 32);
        ay += __shfl_xor(ay, 32);
    }
    if (act && lane < LP) {
        *reinterpret_cast<float2*>(Out + (size_t)node * D + 2 * j) =
            make_float2(ax * dninv_l, ay * dninv_l);
    }
}

// ---------------------------------------------------------------- batchnorm
template <int D>
__global__ void k_bnstats(const float* __restrict__ X, float* __restrict__ colsum,
                          float* __restrict__ colsq) {
    int col = threadIdx.x;
    if (col >= D) return;
    float s = 0.f, q = 0.f;
    for (int r = blockIdx.x; r < NN; r += gridDim.x) {
        float v = X[(size_t)r * D + col];
        s += v;
        q += v * v;
    }
    atomicAdd(&colsum[col], s);
    atomicAdd(&colsq[col], q);
}

// MODE 0: out = elu(bn(x));  MODE 1: out = res + elu(bn(x)).  In-place safe.
template <int D, int MODE>
__global__ void k_bnapply(const float* __restrict__ X, const float* __restrict__ colsum,
                          const float* __restrict__ colsq, const float* __restrict__ g,
                          const float* __restrict__ be, const float* __restrict__ res,
                          float* __restrict__ Out) {
    int idx = blockIdx.x * blockDim.x + threadIdx.x;
    if (idx >= NN * D) return;
    int col = idx % D;
    float mu = colsum[col] * (1.f / NN);
    float var = colsq[col] * (1.f / NN) - mu * mu;
    float sc = g[col] * rsqrtf(var + 1e-5f);
    float v = sc * (X[idx] - mu) + be[col];
    v = (v > 0.f) ? v : (__expf(v) - 1.f);
    if (MODE == 1) v += res[idx];
    Out[idx] = v;
}

// Layer 3: fused BN + log_softmax over 40 classes; one wave per node.
__global__ void k_bn_logsoftmax(const float* __restrict__ X, const float* __restrict__ colsum,
                                const float* __restrict__ colsq, const float* __restrict__ g,
                                const float* __restrict__ be, float* __restrict__ Out) {
    int node = (blockIdx.x * blockDim.x + threadIdx.x) >> 6;
    int lane = threadIdx.x & 63;
    if (node >= NN) return;
    float bnv = 0.f, v = -1e30f;
    if (lane < 40) {
        float mu = colsum[lane] * (1.f / NN);
        float var = colsq[lane] * (1.f / NN) - mu * mu;
        float sc = g[lane] * rsqrtf(var + 1e-5f);
        bnv = sc * (X[node * 40 + lane] - mu) + be[lane];
        v = bnv;
    }
    float m = v;
    for (int off = 32; off; off >>= 1) m = fmaxf(m, __shfl_xor(m, off));
    float ex = (lane < 40) ? expf(bnv - m) : 0.f;
    for (int off = 32; off; off >>= 1) ex += __shfl_xor(ex, off);
    float lse = m + logf(ex);
    if (lane < 40) Out[node * 40 + lane] = bnv - lse;
}

// ---------------------------------------------------------------- launch
extern "C" void kernel_launch(void* const* d_in, const int* in_sizes, int n_in,
                              void* d_out, int out_size, void* d_ws, size_t ws_size,
                              hipStream_t stream) {
    (void)in_sizes; (void)n_in; (void)out_size; (void)ws_size;
    const float* x   = (const float*)d_in[0];
    const int*   ei  = (const int*)d_in[1];
    const float* W1  = (const float*)d_in[2];
    const float* as1 = (const float*)d_in[3];
    const float* ad1 = (const float*)d_in[4];
    const float* g1  = (const float*)d_in[6];
    const float* be1 = (const float*)d_in[7];
    const float* Wm  = (const float*)d_in[8];
    const float* asm_ = (const float*)d_in[9];
    const float* adm = (const float*)d_in[10];
    const float* gm  = (const float*)d_in[12];
    const float* bem = (const float*)d_in[13];
    const float* W2  = (const float*)d_in[14];
    const float* as2 = (const float*)d_in[15];
    const float* ad2 = (const float*)d_in[16];
    const float* g2  = (const float*)d_in[18];
    const float* be2 = (const float*)d_in[19];
    const float* W3  = (const float*)d_in[20];
    const float* as3 = (const float*)d_in[21];
    const float* ad3 = (const float*)d_in[22];
    const float* g3  = (const float*)d_in[24];
    const float* be3 = (const float*)d_in[25];
    float* out = (float*)d_out;
    // GAT biases b1/bm/b2/b3 cancel inside the immediately-following BN (mean-subtract).

    char* ws = (char*)d_ws;
    size_t off = 0;
    auto alloc = [&](size_t b) {
        void* p = ws + off;
        off = (off + b + 255) & ~(size_t)255;
        return p;
    };
    int* rowptr = (int*)alloc((NN + 1) * 4);
    int* csr    = (int*)alloc((size_t)ET * 4);
    int* deg    = (int*)alloc(NN * 4);   // also reused as fill cursor
    int* tmp    = (int*)alloc(NN * 4);
    int* csum   = (int*)alloc(256 * 4);
    bf16* Hbf   = (bf16*)alloc((size_t)NN * 128 * 2);
    float* A    = (float*)alloc((size_t)NN * 128 * 4);
    float* B    = (float*)alloc((size_t)NN * 128 * 4);
    float* S    = (float*)alloc((size_t)NN * 8 * 4);
    float* Dv   = (float*)alloc((size_t)NN * 8 * 4);
    float* cs   = (float*)alloc(256 * 4);
    float* cq   = cs + 128;
    short* WT1  = (short*)alloc(128 * 128 * 2);
    short* WTm  = (short*)alloc(128 * 128 * 2);
    short* WT2  = (short*)alloc(128 * 64 * 2);

    const int nchunks = (NN + 1023) / 1024;

    // ---- weight transpose+convert (tiny)
    k_wconv<128, 128><<<64, 256, 0, stream>>>(W1, WT1);
    k_wconv<128, 128><<<64, 256, 0, stream>>>(Wm, WTm);
    k_wconv<128, 64><<<32, 256, 0, stream>>>(W2, WT2);

    // ---- CSR build (rebuilt every call; ws is re-poisoned by harness)
    hipMemsetAsync(deg, 0, NN * 4, stream);
    k_hist<<<(ET + 255) / 256, 256, 0, stream>>>(ei, deg);
    k_scan_local<<<nchunks, 1024, 0, stream>>>(deg, tmp, csum);
    k_scan_chunks<<<1, 64, 0, stream>>>(csum, nchunks);
    k_rowptr<<<(NN + 255) / 256, 256, 0, stream>>>(tmp, csum, rowptr);
    hipMemsetAsync(deg, 0, NN * 4, stream);
    k_fill<<<(ET + 255) / 256, 256, 0, stream>>>(ei, rowptr, deg, csr);

    const int mfma_blocks = NN / 16;  // 3125, exact
    const int node_wave_blocks = (NN + 3) / 4; // 4 waves of 64 per 256-thread block

    // ---- Layer 1: IN=128 -> H=8 x C=16 (concat, D=128); BN; ELU -> B (= residual)
    k_gemm_mfma<128, 8><<<mfma_blocks, 64, 0, stream>>>(x, WT1, Hbf, as1, ad1, S, Dv);
    k_aggregate<8, 16, 128><<<node_wave_blocks, 256, 0, stream>>>(Hbf, S, Dv, rowptr, csr, A);
    hipMemsetAsync(cs, 0, 256 * 4, stream);
    k_bnstats<128><<<512, 128, 0, stream>>>(A, cs, cq);
    k_bnapply<128, 0><<<(NN * 128 + 255) / 256, 256, 0, stream>>>(A, cs, cq, g1, be1, nullptr, B);

    // ---- Mid layer: 128 -> 128, H=1 (scores fused); BN; ELU; + residual(B) -> A
    k_gemm_mfma<128, 1><<<mfma_blocks, 64, 0, stream>>>(B, WTm, Hbf, asm_, adm, S, Dv);
    k_aggregate<1, 128, 128><<<node_wave_blocks, 256, 0, stream>>>(Hbf, S, Dv, rowptr, csr, A);
    hipMemsetAsync(cs, 0, 256 * 4, stream);
    k_bnstats<128><<<512, 128, 0, stream>>>(A, cs, cq);
    k_bnapply<128, 1><<<(NN * 128 + 255) / 256, 256, 0, stream>>>(A, cs, cq, gm, bem, B, A);

    // ---- Layer 2: 128 -> H=4 x C=16 (concat, D=64); BN; ELU -> B (in-place over agg)
    k_gemm_mfma<64, 4><<<mfma_blocks, 64, 0, stream>>>(A, WT2, Hbf, as2, ad2, S, Dv);
    k_aggregate<4, 16, 64><<<node_wave_blocks, 256, 0, stream>>>(Hbf, S, Dv, rowptr, csr, B);
    hipMemsetAsync(cs, 0, 256 * 4, stream);
    k_bnstats<64><<<512, 64, 0, stream>>>(B, cs, cq);
    k_bnapply<64, 0><<<(NN * 64 + 255) / 256, 256, 0, stream>>>(B, cs, cq, g2, be2, nullptr, B);

    // ---- Layer 3: 64 -> 40, H=1 (scores fused into GEMM); BN; log_softmax -> out
    k_gemm_small<<<NN, 64, 0, stream>>>(B, W3, Hbf, as3, ad3, S, Dv);
    k_aggregate<1, 40, 40><<<node_wave_blocks, 256, 0, stream>>>(Hbf, S, Dv, rowptr, csr, A);
    hipMemsetAsync(cs, 0, 256 * 4, stream);
    k_bnstats<40><<<512, 64, 0, stream>>>(A, cs, cq);
    k_bn_logsoftmax<<<node_wave_blocks, 256, 0, stream>>>(A, cs, cq, g3, be3, out);
}

// Round 8
// 624.848 us; speedup vs baseline: 1.3707x; 1.0001x over previous
//
#include <hip/hip_runtime.h>
#include <hip/hip_bf16.h>
#include <math.h>

#define NN 50000
#define NE 600000
#define ET (NN + NE)   // 650000 edges incl. self-loops

typedef __hip_bfloat16 bf16;
typedef __attribute__((ext_vector_type(8))) short bf16x8;
typedef __attribute__((ext_vector_type(4))) float f32x4;

static __device__ inline unsigned short f2bf(float f) {
    union { __hip_bfloat16 h; unsigned short u; } v;
    v.h = __float2bfloat16(f);
    return v.u;
}
static __device__ inline float bf2f(bf16 h) { return __bfloat162float(h); }

// ---------------------------------------------------------------- CSR build
__global__ void k_hist(const int* __restrict__ ei, int* __restrict__ deg) {
    int e = blockIdx.x * blockDim.x + threadIdx.x;
    if (e >= ET) return;
    int d = (e < NE) ? ei[NE + e] : (e - NE);
    atomicAdd(&deg[d], 1);
}

__global__ void k_scan_local(const int* __restrict__ deg, int* __restrict__ tmp,
                             int* __restrict__ csum) {
    __shared__ int wsum[16];
    int i = blockIdx.x * 1024 + threadIdx.x;
    int lane = threadIdx.x & 63, wid = threadIdx.x >> 6;
    int x = (i < NN) ? deg[i] : 0;
    for (int off = 1; off < 64; off <<= 1) {
        int y = __shfl_up(x, off);
        if (lane >= off) x += y;
    }
    if (lane == 63) wsum[wid] = x;
    __syncthreads();
    if (wid == 0) {
        int t = (lane < 16) ? wsum[lane] : 0;
        for (int off = 1; off < 16; off <<= 1) {
            int y = __shfl_up(t, off);
            if (lane >= off) t += y;
        }
        if (lane < 16) wsum[lane] = t;
    }
    __syncthreads();
    if (wid > 0) x += wsum[wid - 1];
    if (i < NN) tmp[i] = x;                       // inclusive within chunk
    if (threadIdx.x == 1023) csum[blockIdx.x] = x; // chunk total
}

__global__ void k_scan_chunks(int* __restrict__ csum, int nchunks) {
    int lane = threadIdx.x;
    int v = (lane < nchunks) ? csum[lane] : 0;
    for (int off = 1; off < 64; off <<= 1) {
        int y = __shfl_up(v, off);
        if (lane >= off) v += y;
    }
    if (lane < nchunks) csum[lane] = v; // inclusive chunk prefix
}

__global__ void k_rowptr(const int* __restrict__ tmp, const int* __restrict__ csum,
                         int* __restrict__ rowptr) {
    int i = blockIdx.x * blockDim.x + threadIdx.x;
    if (i == 0) rowptr[0] = 0;
    if (i < NN) {
        int chunk = i >> 10;
        int off = (chunk > 0) ? csum[chunk - 1] : 0;
        rowptr[i + 1] = tmp[i] + off;
    }
}

__global__ void k_fill(const int* __restrict__ ei, const int* __restrict__ rowptr,
                       int* __restrict__ fill, int* __restrict__ csr) {
    int e = blockIdx.x * blockDim.x + threadIdx.x;
    if (e >= ET) return;
    int s = (e < NE) ? ei[e] : (e - NE);
    int d = (e < NE) ? ei[NE + e] : (e - NE);
    int pos = atomicAdd(&fill[d], 1);
    csr[rowptr[d] + pos] = s;
}

// ---------------------------------------------------------------- weight transpose+convert
// W [K][D] fp32 -> WT [D][K] bf16 (tiny; L1-resident thereafter)
template <int K, int D>
__global__ void k_wconv(const float* __restrict__ W, short* __restrict__ WT) {
    int idx = blockIdx.x * 256 + threadIdx.x;
    if (idx >= K * D) return;
    int d = idx / K, k = idx % K;
    WT[idx] = (short)f2bf(W[k * D + d]);
}

// ---------------------------------------------------------------- MFMA GEMM (K=128 fixed)
// One wave per 16-row tile; grid = NN/16 = 3125. No LDS, no barrier.
// B16: input is bf16 (direct 16B frag load); else fp32 converted in-register.
// C/D: row=(lane>>4)*4+reg, col=lane&15. HF: fused heads (C=16 -> head==col-tile n).
template <int D, int HF, bool B16>
__global__ __launch_bounds__(64) void k_gemm_mfma(const float* __restrict__ Xf,
                                                  const bf16* __restrict__ Xh,
                                                  const short* __restrict__ WT,
                                                  bf16* __restrict__ Hout,
                                                  const float* __restrict__ a_s,
                                                  const float* __restrict__ a_d,
                                                  float* __restrict__ S,
                                                  float* __restrict__ Dv) {
    constexpr int K = 128;
    constexpr int NT = D / 16;
    int lane = threadIdx.x;
    int rb = blockIdx.x * 16;
    int m = lane & 15, kg = lane >> 4;

    f32x4 acc[NT];
#pragma unroll
    for (int n = 0; n < NT; n++) acc[n] = (f32x4){0.f, 0.f, 0.f, 0.f};

#pragma unroll
    for (int k0 = 0; k0 < K; k0 += 32) {
        bf16x8 a;
        if constexpr (B16) {
            a = *reinterpret_cast<const bf16x8*>(Xh + (size_t)(rb + m) * K + k0 + kg * 8);
        } else {
            const float* xp = Xf + (size_t)(rb + m) * K + k0 + kg * 8;
            float4 f0 = *reinterpret_cast<const float4*>(xp);
            float4 f1 = *reinterpret_cast<const float4*>(xp + 4);
            a[0] = (short)f2bf(f0.x); a[1] = (short)f2bf(f0.y);
            a[2] = (short)f2bf(f0.z); a[3] = (short)f2bf(f0.w);
            a[4] = (short)f2bf(f1.x); a[5] = (short)f2bf(f1.y);
            a[6] = (short)f2bf(f1.z); a[7] = (short)f2bf(f1.w);
        }
#pragma unroll
        for (int n = 0; n < NT; n++) {
            bf16x8 b = *reinterpret_cast<const bf16x8*>(WT + (size_t)(n * 16 + m) * K + k0 + kg * 8);
            acc[n] = __builtin_amdgcn_mfma_f32_16x16x32_bf16(a, b, acc[n], 0, 0, 0);
        }
    }

    float asv[NT], adv[NT];
#pragma unroll
    for (int n = 0; n < NT; n++) {
        asv[n] = a_s[n * 16 + m];
        adv[n] = a_d[n * 16 + m];
    }
#pragma unroll
    for (int r = 0; r < 4; r++) {
        int row = rb + kg * 4 + r;
#pragma unroll
        for (int n = 0; n < NT; n++)
            Hout[(size_t)row * D + n * 16 + m] = __float2bfloat16(acc[n][r]);
        if constexpr (HF == 1) {
            float sa = 0.f, da = 0.f;
#pragma unroll
            for (int n = 0; n < NT; n++) {
                sa += acc[n][r] * asv[n];
                da += acc[n][r] * adv[n];
            }
            for (int off = 1; off < 16; off <<= 1) {
                sa += __shfl_xor(sa, off);
                da += __shfl_xor(da, off);
            }
            if (m == 0) { S[row] = sa; Dv[row] = da; }
        } else {
#pragma unroll
            for (int n = 0; n < NT; n++) {
                float sa = acc[n][r] * asv[n];
                float da = acc[n][r] * adv[n];
                for (int off = 1; off < 16; off <<= 1) {
                    sa += __shfl_xor(sa, off);
                    da += __shfl_xor(da, off);
                }
                if (m == 0) { S[row * HF + n] = sa; Dv[row * HF + n] = da; }
            }
        }
    }
}

// K=64, D=40 (layer 3): one node per 64-thread block; bf16 input; fused H=1 scores.
__global__ void k_gemm_small(const bf16* __restrict__ X, const float* __restrict__ W,
                             bf16* __restrict__ Hout, const float* __restrict__ a_s,
                             const float* __restrict__ a_d, float* __restrict__ S,
                             float* __restrict__ Dv) {
    __shared__ float xs[64];
    int n = blockIdx.x, t = threadIdx.x;
    xs[t] = bf2f(X[n * 64 + t]);
    __syncthreads();
    float acc = 0.f;
    if (t < 40) {
#pragma unroll
        for (int k = 0; k < 64; k++) acc += xs[k] * W[k * 40 + t];
        Hout[n * 40 + t] = __float2bfloat16(acc);
    }
    float sa = (t < 40) ? acc * a_s[t] : 0.f;
    float da = (t < 40) ? acc * a_d[t] : 0.f;
    for (int off = 32; off; off >>= 1) {
        sa += __shfl_xor(sa, off);
        da += __shfl_xor(da, off);
    }
    if (t == 0) {
        S[n] = sa;
        Dv[n] = da;
    }
}

// ---------------------------------------------------------------- aggregation
// One wave per node; phase-1 LDS weight cache; phase-2 8-way unrolled gather;
// bf16 output (packed 2-col writes).
template <int H, int C, int D>
__global__ __launch_bounds__(256) void k_aggregate(const bf16* __restrict__ Hb,
                                                   const float* __restrict__ S,
                                                   const float* __restrict__ Dv,
                                                   const int* __restrict__ rowptr,
                                                   const int* __restrict__ csr,
                                                   bf16* __restrict__ Out) {
    constexpr int WCAP = 64;
    __shared__ float wl[4][WCAP * H];
    int nl = threadIdx.x >> 6;
    int node = blockIdx.x * 4 + nl;
    if (node >= NN) return;
    int lane = threadIdx.x & 63;
    int r0 = rowptr[node], r1 = rowptr[node + 1];
    int cnt = r1 - r0;
    float dn[H], den[H];
#pragma unroll
    for (int h = 0; h < H; h++) {
        dn[h] = Dv[node * H + h];
        den[h] = 0.f;
    }
    // phase 1: per-edge exp + denominators; cache exp in LDS
    for (int k = lane; k < cnt; k += 64) {
        int u = csr[r0 + k];
        float sv[H];
        if constexpr (H == 8) {
            float4 s0 = *reinterpret_cast<const float4*>(S + (size_t)u * 8);
            float4 s1 = *reinterpret_cast<const float4*>(S + (size_t)u * 8 + 4);
            sv[0] = s0.x; sv[1] = s0.y; sv[2] = s0.z; sv[3] = s0.w;
            sv[4] = s1.x; sv[5] = s1.y; sv[6] = s1.z; sv[7] = s1.w;
        } else if constexpr (H == 4) {
            float4 s0 = *reinterpret_cast<const float4*>(S + (size_t)u * 4);
            sv[0] = s0.x; sv[1] = s0.y; sv[2] = s0.z; sv[3] = s0.w;
        } else {
            sv[0] = S[u];
        }
        float ex[H];
#pragma unroll
        for (int h = 0; h < H; h++) {
            float e = sv[h] + dn[h];
            e = fmaxf(e, 0.2f * e);  // leaky_relu
            ex[h] = __expf(e);
            den[h] += ex[h];
        }
        if (k < WCAP) {
#pragma unroll
            for (int h = 0; h < H; h++) wl[nl][k * H + h] = ex[h];
        }
    }
#pragma unroll
    for (int h = 0; h < H; h++) {
        for (int off = 32; off; off >>= 1) den[h] += __shfl_xor(den[h], off);
        den[h] = 1.f / (den[h] + 1e-16f);
    }
    // no __syncthreads needed: each wave reads only the LDS segment it wrote

    // phase 2: weighted aggregation over bf16 rows
    constexpr int EPI = (D > 64) ? 1 : 2;  // edges per iteration
    constexpr int LP = 64 / EPI;           // lanes per edge
    int sub = lane / LP;
    int j = lane % LP;          // column pair (2j, 2j+1)
    bool act = (2 * j) < D;
    const int h_l = act ? (2 * j) / C : 0;  // lane-constant head
    float dninv_l = den[0], dn_l = dn[0];
#pragma unroll
    for (int h = 1; h < H; h++) {
        dninv_l = (h_l == h) ? den[h] : dninv_l;
        dn_l = (h_l == h) ? dn[h] : dn_l;
    }
    const float* wlp = &wl[nl][0];
    auto wof = [&](int idx, int u) -> float {
        if (idx < WCAP) return wlp[idx * H + h_l];  // cached (normal path)
        float e = S[(size_t)u * H + h_l] + dn_l;    // overflow fallback (deg > 64)
        e = fmaxf(e, 0.2f * e);
        return __expf(e);
    };
    float ax = 0.f, ay = 0.f;
    int k = sub;
    for (; k + 7 * EPI < cnt; k += 8 * EPI) {
        int uu[8];
        unsigned pp[8];
#pragma unroll
        for (int i = 0; i < 8; i++) uu[i] = csr[r0 + k + i * EPI];
#pragma unroll
        for (int i = 0; i < 8; i++)
            pp[i] = act ? *reinterpret_cast<const unsigned*>(Hb + (size_t)uu[i] * D + 2 * j) : 0u;
#pragma unroll
        for (int i = 0; i < 8; i++) {
            float w = wof(k + i * EPI, uu[i]);
            ax += w * __uint_as_float(pp[i] << 16);
            ay += w * __uint_as_float(pp[i] & 0xffff0000u);
        }
    }
    for (; k + 3 * EPI < cnt; k += 4 * EPI) {
        int uu[4];
        unsigned pp[4];
#pragma unroll
        for (int i = 0; i < 4; i++) uu[i] = csr[r0 + k + i * EPI];
#pragma unroll
        for (int i = 0; i < 4; i++)
            pp[i] = act ? *reinterpret_cast<const unsigned*>(Hb + (size_t)uu[i] * D + 2 * j) : 0u;
#pragma unroll
        for (int i = 0; i < 4; i++) {
            float w = wof(k + i * EPI, uu[i]);
            ax += w * __uint_as_float(pp[i] << 16);
            ay += w * __uint_as_float(pp[i] & 0xffff0000u);
        }
    }
    for (; k < cnt; k += EPI) {
        int u = csr[r0 + k];
        unsigned pv = 0;
        if (act) pv = *reinterpret_cast<const unsigned*>(Hb + (size_t)u * D + 2 * j);
        float w = wof(k, u);
        ax += w * __uint_as_float(pv << 16);
        ay += w * __uint_as_float(pv & 0xffff0000u);
    }
    if (EPI == 2) {
        ax += __shfl_xor(ax, 32);
        ay += __shfl_xor(ay, 32);
    }
    if (act && lane < LP) {
        unsigned o = (unsigned)f2bf(ax * dninv_l) | ((unsigned)f2bf(ay * dninv_l) << 16);
        *reinterpret_cast<unsigned*>(Out + (size_t)node * D + 2 * j) = o;
    }
}

// ---------------------------------------------------------------- batchnorm (bf16 in)
template <int D>
__global__ void k_bnstats(const bf16* __restrict__ X, float* __restrict__ colsum,
                          float* __restrict__ colsq) {
    int col = threadIdx.x;
    if (col >= D) return;
    float s = 0.f, q = 0.f;
    for (int r = blockIdx.x; r < NN; r += gridDim.x) {
        float v = bf2f(X[(size_t)r * D + col]);
        s += v;
        q += v * v;
    }
    atomicAdd(&colsum[col], s);
    atomicAdd(&colsq[col], q);
}

// MODE 0: out = elu(bn(x));  MODE 1: out = res + elu(bn(x)).  bf16 in/out.
template <int D, int MODE>
__global__ void k_bnapply(const bf16* __restrict__ X, const float* __restrict__ colsum,
                          const float* __restrict__ colsq, const float* __restrict__ g,
                          const float* __restrict__ be, const bf16* __restrict__ res,
                          bf16* __restrict__ Out) {
    int idx = blockIdx.x * blockDim.x + threadIdx.x;
    if (idx >= NN * D) return;
    int col = idx % D;
    float mu = colsum[col] * (1.f / NN);
    float var = colsq[col] * (1.f / NN) - mu * mu;
    float sc = g[col] * rsqrtf(var + 1e-5f);
    float v = sc * (bf2f(X[idx]) - mu) + be[col];
    v = (v > 0.f) ? v : (__expf(v) - 1.f);
    if (MODE == 1) v += bf2f(res[idx]);
    Out[idx] = __float2bfloat16(v);
}

// Layer 3: fused BN + log_softmax over 40 classes; one wave per node. bf16 in, fp32 out.
__global__ void k_bn_logsoftmax(const bf16* __restrict__ X, const float* __restrict__ colsum,
                                const float* __restrict__ colsq, const float* __restrict__ g,
                                const float* __restrict__ be, float* __restrict__ Out) {
    int node = (blockIdx.x * blockDim.x + threadIdx.x) >> 6;
    int lane = threadIdx.x & 63;
    if (node >= NN) return;
    float bnv = 0.f, v = -1e30f;
    if (lane < 40) {
        float mu = colsum[lane] * (1.f / NN);
        float var = colsq[lane] * (1.f / NN) - mu * mu;
        float sc = g[lane] * rsqrtf(var + 1e-5f);
        bnv = sc * (bf2f(X[node * 40 + lane]) - mu) + be[lane];
        v = bnv;
    }
    float m = v;
    for (int off = 32; off; off >>= 1) m = fmaxf(m, __shfl_xor(m, off));
    float ex = (lane < 40) ? expf(bnv - m) : 0.f;
    for (int off = 32; off; off >>= 1) ex += __shfl_xor(ex, off);
    float lse = m + logf(ex);
    if (lane < 40) Out[node * 40 + lane] = bnv - lse;
}

// ---------------------------------------------------------------- launch
extern "C" void kernel_launch(void* const* d_in, const int* in_sizes, int n_in,
                              void* d_out, int out_size, void* d_ws, size_t ws_size,
                              hipStream_t stream) {
    (void)in_sizes; (void)n_in; (void)out_size; (void)ws_size;
    const float* x   = (const float*)d_in[0];
    const int*   ei  = (const int*)d_in[1];
    const float* W1  = (const float*)d_in[2];
    const float* as1 = (const float*)d_in[3];
    const float* ad1 = (const float*)d_in[4];
    const float* g1  = (const float*)d_in[6];
    const float* be1 = (const float*)d_in[7];
    const float* Wm  = (const float*)d_in[8];
    const float* asm_ = (const float*)d_in[9];
    const float* adm = (const float*)d_in[10];
    const float* gm  = (const float*)d_in[12];
    const float* bem = (const float*)d_in[13];
    const float* W2  = (const float*)d_in[14];
    const float* as2 = (const float*)d_in[15];
    const float* ad2 = (const float*)d_in[16];
    const float* g2  = (const float*)d_in[18];
    const float* be2 = (const float*)d_in[19];
    const float* W3  = (const float*)d_in[20];
    const float* as3 = (const float*)d_in[21];
    const float* ad3 = (const float*)d_in[22];
    const float* g3  = (const float*)d_in[24];
    const float* be3 = (const float*)d_in[25];
    float* out = (float*)d_out;
    // GAT biases b1/bm/b2/b3 cancel inside the immediately-following BN (mean-subtract).

    char* ws = (char*)d_ws;
    size_t off = 0;
    auto alloc = [&](size_t b) {
        void* p = ws + off;
        off = (off + b + 255) & ~(size_t)255;
        return p;
    };
    int* rowptr = (int*)alloc((NN + 1) * 4);
    int* csr    = (int*)alloc((size_t)ET * 4);
    int* deg    = (int*)alloc(NN * 4);   // also reused as fill cursor
    int* tmp    = (int*)alloc(NN * 4);
    int* csum   = (int*)alloc(256 * 4);
    bf16* Hbf   = (bf16*)alloc((size_t)NN * 128 * 2);
    bf16* AG    = (bf16*)alloc((size_t)NN * 128 * 2);
    bf16* P1    = (bf16*)alloc((size_t)NN * 128 * 2);
    bf16* P2    = (bf16*)alloc((size_t)NN * 128 * 2);
    float* S    = (float*)alloc((size_t)NN * 8 * 4);
    float* Dv   = (float*)alloc((size_t)NN * 8 * 4);
    float* cs   = (float*)alloc(256 * 4);
    float* cq   = cs + 128;
    short* WT1  = (short*)alloc(128 * 128 * 2);
    short* WTm  = (short*)alloc(128 * 128 * 2);
    short* WT2  = (short*)alloc(128 * 64 * 2);

    const int nchunks = (NN + 1023) / 1024;

    // ---- weight transpose+convert (tiny)
    k_wconv<128, 128><<<64, 256, 0, stream>>>(W1, WT1);
    k_wconv<128, 128><<<64, 256, 0, stream>>>(Wm, WTm);
    k_wconv<128, 64><<<32, 256, 0, stream>>>(W2, WT2);

    // ---- CSR build (rebuilt every call; ws is re-poisoned by harness)
    hipMemsetAsync(deg, 0, NN * 4, stream);
    k_hist<<<(ET + 255) / 256, 256, 0, stream>>>(ei, deg);
    k_scan_local<<<nchunks, 1024, 0, stream>>>(deg, tmp, csum);
    k_scan_chunks<<<1, 64, 0, stream>>>(csum, nchunks);
    k_rowptr<<<(NN + 255) / 256, 256, 0, stream>>>(tmp, csum, rowptr);
    hipMemsetAsync(deg, 0, NN * 4, stream);
    k_fill<<<(ET + 255) / 256, 256, 0, stream>>>(ei, rowptr, deg, csr);

    const int mfma_blocks = NN / 16;  // 3125, exact
    const int node_wave_blocks = (NN + 3) / 4; // 4 waves of 64 per 256-thread block

    // ---- Layer 1: IN=128 -> H=8 x C=16 (concat, D=128); BN; ELU -> P1 (= residual)
    k_gemm_mfma<128, 8, false><<<mfma_blocks, 64, 0, stream>>>(x, nullptr, WT1, Hbf, as1, ad1, S, Dv);
    k_aggregate<8, 16, 128><<<node_wave_blocks, 256, 0, stream>>>(Hbf, S, Dv, rowptr, csr, AG);
    hipMemsetAsync(cs, 0, 256 * 4, stream);
    k_bnstats<128><<<512, 128, 0, stream>>>(AG, cs, cq);
    k_bnapply<128, 0><<<(NN * 128 + 255) / 256, 256, 0, stream>>>(AG, cs, cq, g1, be1, nullptr, P1);

    // ---- Mid layer: 128 -> 128, H=1 (scores fused); BN; ELU; + residual(P1) -> P2
    k_gemm_mfma<128, 1, true><<<mfma_blocks, 64, 0, stream>>>(nullptr, P1, WTm, Hbf, asm_, adm, S, Dv);
    k_aggregate<1, 128, 128><<<node_wave_blocks, 256, 0, stream>>>(Hbf, S, Dv, rowptr, csr, AG);
    hipMemsetAsync(cs, 0, 256 * 4, stream);
    k_bnstats<128><<<512, 128, 0, stream>>>(AG, cs, cq);
    k_bnapply<128, 1><<<(NN * 128 + 255) / 256, 256, 0, stream>>>(AG, cs, cq, gm, bem, P1, P2);

    // ---- Layer 2: 128 -> H=4 x C=16 (concat, D=64); BN; ELU -> P1
    k_gemm_mfma<64, 4, true><<<mfma_blocks, 64, 0, stream>>>(nullptr, P2, WT2, Hbf, as2, ad2, S, Dv);
    k_aggregate<4, 16, 64><<<node_wave_blocks, 256, 0, stream>>>(Hbf, S, Dv, rowptr, csr, AG);
    hipMemsetAsync(cs, 0, 256 * 4, stream);
    k_bnstats<64><<<512, 64, 0, stream>>>(AG, cs, cq);
    k_bnapply<64, 0><<<(NN * 64 + 255) / 256, 256, 0, stream>>>(AG, cs, cq, g2, be2, nullptr, P1);

    // ---- Layer 3: 64 -> 40, H=1 (scores fused into GEMM); BN; log_softmax -> out
    k_gemm_small<<<NN, 64, 0, stream>>>(P1, W3, Hbf, as3, ad3, S, Dv);
    k_aggregate<1, 40, 40><<<node_wave_blocks, 256, 0, stream>>>(Hbf, S, Dv, rowptr, csr, AG);
    hipMemsetAsync(cs, 0, 256 * 4, stream);
    k_bnstats<40><<<512, 64, 0, stream>>>(AG, cs, cq);
    k_bn_logsoftmax<<<node_wave_blocks, 256, 0, stream>>>(AG, cs, cq, g3, be3, out);
}

// Round 9
// 580.980 us; speedup vs baseline: 1.4742x; 1.0755x over previous
//
#include <hip/hip_runtime.h>
#include <hip/hip_bf16.h>
#include <math.h>

#define NN 50000
#define NE 600000
#define ET (NN + NE)   // 650000 edges incl. self-loops

typedef __hip_bfloat16 bf16;
typedef __attribute__((ext_vector_type(8))) short bf16x8;
typedef __attribute__((ext_vector_type(4))) float f32x4;

static __device__ inline unsigned short f2bf(float f) {
    union { __hip_bfloat16 h; unsigned short u; } v;
    v.h = __float2bfloat16(f);
    return v.u;
}
static __device__ inline float bf2f(bf16 h) { return __bfloat162float(h); }

// ---------------------------------------------------------------- CSR build
__global__ void k_hist(const int* __restrict__ ei, int* __restrict__ deg) {
    int e = blockIdx.x * blockDim.x + threadIdx.x;
    if (e >= ET) return;
    int d = (e < NE) ? ei[NE + e] : (e - NE);
    atomicAdd(&deg[d], 1);
}

__global__ void k_scan_local(const int* __restrict__ deg, int* __restrict__ tmp,
                             int* __restrict__ csum) {
    __shared__ int wsum[16];
    int i = blockIdx.x * 1024 + threadIdx.x;
    int lane = threadIdx.x & 63, wid = threadIdx.x >> 6;
    int x = (i < NN) ? deg[i] : 0;
    for (int off = 1; off < 64; off <<= 1) {
        int y = __shfl_up(x, off);
        if (lane >= off) x += y;
    }
    if (lane == 63) wsum[wid] = x;
    __syncthreads();
    if (wid == 0) {
        int t = (lane < 16) ? wsum[lane] : 0;
        for (int off = 1; off < 16; off <<= 1) {
            int y = __shfl_up(t, off);
            if (lane >= off) t += y;
        }
        if (lane < 16) wsum[lane] = t;
    }
    __syncthreads();
    if (wid > 0) x += wsum[wid - 1];
    if (i < NN) tmp[i] = x;                       // inclusive within chunk
    if (threadIdx.x == 1023) csum[blockIdx.x] = x; // chunk total
}

__global__ void k_scan_chunks(int* __restrict__ csum, int nchunks) {
    int lane = threadIdx.x;
    int v = (lane < nchunks) ? csum[lane] : 0;
    for (int off = 1; off < 64; off <<= 1) {
        int y = __shfl_up(v, off);
        if (lane >= off) v += y;
    }
    if (lane < nchunks) csum[lane] = v; // inclusive chunk prefix
}

__global__ void k_rowptr(const int* __restrict__ tmp, const int* __restrict__ csum,
                         int* __restrict__ rowptr) {
    int i = blockIdx.x * blockDim.x + threadIdx.x;
    if (i == 0) rowptr[0] = 0;
    if (i < NN) {
        int chunk = i >> 10;
        int off = (chunk > 0) ? csum[chunk - 1] : 0;
        rowptr[i + 1] = tmp[i] + off;
    }
}

__global__ void k_fill(const int* __restrict__ ei, const int* __restrict__ rowptr,
                       int* __restrict__ fill, int* __restrict__ csr) {
    int e = blockIdx.x * blockDim.x + threadIdx.x;
    if (e >= ET) return;
    int s = (e < NE) ? ei[e] : (e - NE);
    int d = (e < NE) ? ei[NE + e] : (e - NE);
    int pos = atomicAdd(&fill[d], 1);
    csr[rowptr[d] + pos] = s;
}

// ---------------------------------------------------------------- weight transpose+convert (all 3 in one)
__global__ void k_wconv_all(const float* __restrict__ W1, const float* __restrict__ Wm,
                            const float* __restrict__ W2, short* __restrict__ WT1,
                            short* __restrict__ WTm, short* __restrict__ WT2) {
    int idx = blockIdx.x * 256 + threadIdx.x;
    if (idx < 16384) {                       // W1: [128][128] -> WT1 [128][128]
        int d = idx >> 7, k = idx & 127;
        WT1[idx] = (short)f2bf(W1[k * 128 + d]);
    } else if (idx < 32768) {                // Wm
        int i2 = idx - 16384;
        int d = i2 >> 7, k = i2 & 127;
        WTm[i2] = (short)f2bf(Wm[k * 128 + d]);
    } else if (idx < 40960) {                // W2: [128][64] -> WT2 [64][128]
        int i3 = idx - 32768;
        int d = i3 >> 7, k = i3 & 127;
        WT2[i3] = (short)f2bf(W2[k * 64 + d]);
    }
}

// ---------------------------------------------------------------- BN finalize: sums -> (scale, shift)
template <int D>
__global__ void k_bnfin(const float* __restrict__ sums, const float* __restrict__ g,
                        const float* __restrict__ be, float2* __restrict__ ss) {
    int c = threadIdx.x;
    if (c >= D) return;
    float mu = sums[c] * (1.f / NN);
    float var = sums[128 + c] * (1.f / NN) - mu * mu;
    float sc = g[c] * rsqrtf(var + 1e-5f);
    ss[c] = make_float2(sc, be[c] - mu * sc);
}

// ---------------------------------------------------------------- MFMA GEMM (K=128 fixed)
// One wave per 16-row tile; grid = NN/16 = 3125. No LDS, no barrier.
// MODE 0: fp32 input. MODE 1: bf16 input with fused elu(bn(x)) via (sc,sh).
// MODE 2: MODE 1 + fused residual elu(bn2(x2)) added (layer-2 consumes mid+res).
// C/D: row=(lane>>4)*4+reg, col=lane&15. HF: fused heads (C=16 -> head==col-tile n).
template <int D, int HF, int MODE>
__global__ __launch_bounds__(64) void k_gemm_mfma(const float* __restrict__ Xf,
                                                  const bf16* __restrict__ X1,
                                                  const float2* __restrict__ ss1,
                                                  const bf16* __restrict__ X2,
                                                  const float2* __restrict__ ss2,
                                                  const short* __restrict__ WT,
                                                  bf16* __restrict__ Hout,
                                                  const float* __restrict__ a_s,
                                                  const float* __restrict__ a_d,
                                                  float* __restrict__ S,
                                                  float* __restrict__ Dv) {
    constexpr int K = 128;
    constexpr int NT = D / 16;
    int lane = threadIdx.x;
    int rb = blockIdx.x * 16;
    int m = lane & 15, kg = lane >> 4;

    f32x4 acc[NT];
#pragma unroll
    for (int n = 0; n < NT; n++) acc[n] = (f32x4){0.f, 0.f, 0.f, 0.f};

#pragma unroll
    for (int k0 = 0; k0 < K; k0 += 32) {
        int cb = k0 + kg * 8;
        bf16x8 a;
        if constexpr (MODE == 0) {
            const float* xp = Xf + (size_t)(rb + m) * K + cb;
            float4 f0 = *reinterpret_cast<const float4*>(xp);
            float4 f1 = *reinterpret_cast<const float4*>(xp + 4);
            a[0] = (short)f2bf(f0.x); a[1] = (short)f2bf(f0.y);
            a[2] = (short)f2bf(f0.z); a[3] = (short)f2bf(f0.w);
            a[4] = (short)f2bf(f1.x); a[5] = (short)f2bf(f1.y);
            a[6] = (short)f2bf(f1.z); a[7] = (short)f2bf(f1.w);
        } else {
            bf16x8 r1 = *reinterpret_cast<const bf16x8*>(X1 + (size_t)(rb + m) * K + cb);
            bf16x8 r2;
            if constexpr (MODE == 2)
                r2 = *reinterpret_cast<const bf16x8*>(X2 + (size_t)(rb + m) * K + cb);
#pragma unroll
            for (int j = 0; j < 8; j++) {
                float2 p1 = ss1[cb + j];
                bf16 b1; *(short*)&b1 = r1[j];
                float v = p1.x * bf2f(b1) + p1.y;
                v = (v > 0.f) ? v : (__expf(v) - 1.f);
                if constexpr (MODE == 2) {
                    float2 p2 = ss2[cb + j];
                    bf16 b2; *(short*)&b2 = r2[j];
                    float v2 = p2.x * bf2f(b2) + p2.y;
                    v2 = (v2 > 0.f) ? v2 : (__expf(v2) - 1.f);
                    v += v2;
                }
                a[j] = (short)f2bf(v);
            }
        }
#pragma unroll
        for (int n = 0; n < NT; n++) {
            bf16x8 b = *reinterpret_cast<const bf16x8*>(WT + (size_t)(n * 16 + m) * K + cb);
            acc[n] = __builtin_amdgcn_mfma_f32_16x16x32_bf16(a, b, acc[n], 0, 0, 0);
        }
    }

    float asv[NT], adv[NT];
#pragma unroll
    for (int n = 0; n < NT; n++) {
        asv[n] = a_s[n * 16 + m];
        adv[n] = a_d[n * 16 + m];
    }
#pragma unroll
    for (int r = 0; r < 4; r++) {
        int row = rb + kg * 4 + r;
#pragma unroll
        for (int n = 0; n < NT; n++)
            Hout[(size_t)row * D + n * 16 + m] = __float2bfloat16(acc[n][r]);
        if constexpr (HF == 1) {
            float sa = 0.f, da = 0.f;
#pragma unroll
            for (int n = 0; n < NT; n++) {
                sa += acc[n][r] * asv[n];
                da += acc[n][r] * adv[n];
            }
            for (int off = 1; off < 16; off <<= 1) {
                sa += __shfl_xor(sa, off);
                da += __shfl_xor(da, off);
            }
            if (m == 0) { S[row] = sa; Dv[row] = da; }
        } else {
#pragma unroll
            for (int n = 0; n < NT; n++) {
                float sa = acc[n][r] * asv[n];
                float da = acc[n][r] * adv[n];
                for (int off = 1; off < 16; off <<= 1) {
                    sa += __shfl_xor(sa, off);
                    da += __shfl_xor(da, off);
                }
                if (m == 0) { S[row * HF + n] = sa; Dv[row * HF + n] = da; }
            }
        }
    }
}

// K=64, D=40 (layer 3): one node per 64-thread block; fused elu(bn(x)) input + H=1 scores.
__global__ void k_gemm_small(const bf16* __restrict__ X, const float2* __restrict__ ss,
                             const float* __restrict__ W, bf16* __restrict__ Hout,
                             const float* __restrict__ a_s, const float* __restrict__ a_d,
                             float* __restrict__ S, float* __restrict__ Dv) {
    __shared__ float xs[64];
    int n = blockIdx.x, t = threadIdx.x;
    {
        float2 p = ss[t];
        float v = p.x * bf2f(X[n * 64 + t]) + p.y;
        xs[t] = (v > 0.f) ? v : (__expf(v) - 1.f);
    }
    __syncthreads();
    float acc = 0.f;
    if (t < 40) {
#pragma unroll
        for (int k = 0; k < 64; k++) acc += xs[k] * W[k * 40 + t];
        Hout[n * 40 + t] = __float2bfloat16(acc);
    }
    float sa = (t < 40) ? acc * a_s[t] : 0.f;
    float da = (t < 40) ? acc * a_d[t] : 0.f;
    for (int off = 32; off; off >>= 1) {
        sa += __shfl_xor(sa, off);
        da += __shfl_xor(da, off);
    }
    if (t == 0) {
        S[n] = sa;
        Dv[n] = da;
    }
}

// ---------------------------------------------------------------- aggregation
// One wave per node; phase-1 LDS weight cache; phase-2 4-way unrolled gather
// (8-way regressed in R8: VGPR 32->44, occupancy 63->42%); bf16 packed output.
template <int H, int C, int D>
__global__ __launch_bounds__(256) void k_aggregate(const bf16* __restrict__ Hb,
                                                   const float* __restrict__ S,
                                                   const float* __restrict__ Dv,
                                                   const int* __restrict__ rowptr,
                                                   const int* __restrict__ csr,
                                                   bf16* __restrict__ Out) {
    constexpr int WCAP = 64;
    __shared__ float wl[4][WCAP * H];
    int nl = threadIdx.x >> 6;
    int node = blockIdx.x * 4 + nl;
    if (node >= NN) return;
    int lane = threadIdx.x & 63;
    int r0 = rowptr[node], r1 = rowptr[node + 1];
    int cnt = r1 - r0;
    float dn[H], den[H];
#pragma unroll
    for (int h = 0; h < H; h++) {
        dn[h] = Dv[node * H + h];
        den[h] = 0.f;
    }
    // phase 1: per-edge exp + denominators; cache exp in LDS
    for (int k = lane; k < cnt; k += 64) {
        int u = csr[r0 + k];
        float sv[H];
        if constexpr (H == 8) {
            float4 s0 = *reinterpret_cast<const float4*>(S + (size_t)u * 8);
            float4 s1 = *reinterpret_cast<const float4*>(S + (size_t)u * 8 + 4);
            sv[0] = s0.x; sv[1] = s0.y; sv[2] = s0.z; sv[3] = s0.w;
            sv[4] = s1.x; sv[5] = s1.y; sv[6] = s1.z; sv[7] = s1.w;
        } else if constexpr (H == 4) {
            float4 s0 = *reinterpret_cast<const float4*>(S + (size_t)u * 4);
            sv[0] = s0.x; sv[1] = s0.y; sv[2] = s0.z; sv[3] = s0.w;
        } else {
            sv[0] = S[u];
        }
        float ex[H];
#pragma unroll
        for (int h = 0; h < H; h++) {
            float e = sv[h] + dn[h];
            e = fmaxf(e, 0.2f * e);  // leaky_relu
            ex[h] = __expf(e);
            den[h] += ex[h];
        }
        if (k < WCAP) {
#pragma unroll
            for (int h = 0; h < H; h++) wl[nl][k * H + h] = ex[h];
        }
    }
#pragma unroll
    for (int h = 0; h < H; h++) {
        for (int off = 32; off; off >>= 1) den[h] += __shfl_xor(den[h], off);
        den[h] = 1.f / (den[h] + 1e-16f);
    }
    // no __syncthreads needed: each wave reads only the LDS segment it wrote

    // phase 2: weighted aggregation over bf16 rows
    constexpr int EPI = (D > 64) ? 1 : 2;  // edges per iteration
    constexpr int LP = 64 / EPI;           // lanes per edge
    int sub = lane / LP;
    int j = lane % LP;          // column pair (2j, 2j+1)
    bool act = (2 * j) < D;
    const int h_l = act ? (2 * j) / C : 0;  // lane-constant head
    float dninv_l = den[0], dn_l = dn[0];
#pragma unroll
    for (int h = 1; h < H; h++) {
        dninv_l = (h_l == h) ? den[h] : dninv_l;
        dn_l = (h_l == h) ? dn[h] : dn_l;
    }
    const float* wlp = &wl[nl][0];
    auto wof = [&](int idx, int u) -> float {
        if (idx < WCAP) return wlp[idx * H + h_l];  // cached (normal path)
        float e = S[(size_t)u * H + h_l] + dn_l;    // overflow fallback (deg > 64)
        e = fmaxf(e, 0.2f * e);
        return __expf(e);
    };
    float ax = 0.f, ay = 0.f;
    int k = sub;
    for (; k + 3 * EPI < cnt; k += 4 * EPI) {
        int u0 = csr[r0 + k];
        int u1 = csr[r0 + k + EPI];
        int u2 = csr[r0 + k + 2 * EPI];
        int u3 = csr[r0 + k + 3 * EPI];
        unsigned p0 = 0, p1 = 0, p2 = 0, p3 = 0;
        if (act) {
            p0 = *reinterpret_cast<const unsigned*>(Hb + (size_t)u0 * D + 2 * j);
            p1 = *reinterpret_cast<const unsigned*>(Hb + (size_t)u1 * D + 2 * j);
            p2 = *reinterpret_cast<const unsigned*>(Hb + (size_t)u2 * D + 2 * j);
            p3 = *reinterpret_cast<const unsigned*>(Hb + (size_t)u3 * D + 2 * j);
        }
        float w0 = wof(k, u0), w1 = wof(k + EPI, u1);
        float w2 = wof(k + 2 * EPI, u2), w3 = wof(k + 3 * EPI, u3);
        ax += w0 * __uint_as_float(p0 << 16) + w1 * __uint_as_float(p1 << 16) +
              w2 * __uint_as_float(p2 << 16) + w3 * __uint_as_float(p3 << 16);
        ay += w0 * __uint_as_float(p0 & 0xffff0000u) + w1 * __uint_as_float(p1 & 0xffff0000u) +
              w2 * __uint_as_float(p2 & 0xffff0000u) + w3 * __uint_as_float(p3 & 0xffff0000u);
    }
    for (; k < cnt; k += EPI) {
        int u = csr[r0 + k];
        unsigned pv = 0;
        if (act) pv = *reinterpret_cast<const unsigned*>(Hb + (size_t)u * D + 2 * j);
        float w = wof(k, u);
        ax += w * __uint_as_float(pv << 16);
        ay += w * __uint_as_float(pv & 0xffff0000u);
    }
    if (EPI == 2) {
        ax += __shfl_xor(ax, 32);
        ay += __shfl_xor(ay, 32);
    }
    if (act && lane < LP) {
        unsigned o = (unsigned)f2bf(ax * dninv_l) | ((unsigned)f2bf(ay * dninv_l) << 16);
        *reinterpret_cast<unsigned*>(Out + (size_t)node * D + 2 * j) = o;
    }
}

// ---------------------------------------------------------------- batchnorm stats (bf16 in)
template <int D>
__global__ void k_bnstats(const bf16* __restrict__ X, float* __restrict__ sums) {
    int col = threadIdx.x;
    if (col >= D) return;
    float s = 0.f, q = 0.f;
    for (int r = blockIdx.x; r < NN; r += gridDim.x) {
        float v = bf2f(X[(size_t)r * D + col]);
        s += v;
        q += v * v;
    }
    atomicAdd(&sums[col], s);
    atomicAdd(&sums[128 + col], q);
}

// Layer 3: fused BN + log_softmax over 40 classes; one wave per node. bf16 in, fp32 out.
__global__ void k_bn_logsoftmax(const bf16* __restrict__ X, const float* __restrict__ sums,
                                const float* __restrict__ g, const float* __restrict__ be,
                                float* __restrict__ Out) {
    int node = (blockIdx.x * blockDim.x + threadIdx.x) >> 6;
    int lane = threadIdx.x & 63;
    if (node >= NN) return;
    float bnv = 0.f, v = -1e30f;
    if (lane < 40) {
        float mu = sums[lane] * (1.f / NN);
        float var = sums[128 + lane] * (1.f / NN) - mu * mu;
        float sc = g[lane] * rsqrtf(var + 1e-5f);
        bnv = sc * (bf2f(X[node * 40 + lane]) - mu) + be[lane];
        v = bnv;
    }
    float m = v;
    for (int off = 32; off; off >>= 1) m = fmaxf(m, __shfl_xor(m, off));
    float ex = (lane < 40) ? expf(bnv - m) : 0.f;
    for (int off = 32; off; off >>= 1) ex += __shfl_xor(ex, off);
    float lse = m + logf(ex);
    if (lane < 40) Out[node * 40 + lane] = bnv - lse;
}

// ---------------------------------------------------------------- launch
extern "C" void kernel_launch(void* const* d_in, const int* in_sizes, int n_in,
                              void* d_out, int out_size, void* d_ws, size_t ws_size,
                              hipStream_t stream) {
    (void)in_sizes; (void)n_in; (void)out_size; (void)ws_size;
    const float* x   = (const float*)d_in[0];
    const int*   ei  = (const int*)d_in[1];
    const float* W1  = (const float*)d_in[2];
    const float* as1 = (const float*)d_in[3];
    const float* ad1 = (const float*)d_in[4];
    const float* g1  = (const float*)d_in[6];
    const float* be1 = (const float*)d_in[7];
    const float* Wm  = (const float*)d_in[8];
    const float* asm_ = (const float*)d_in[9];
    const float* adm = (const float*)d_in[10];
    const float* gm  = (const float*)d_in[12];
    const float* bem = (const float*)d_in[13];
    const float* W2  = (const float*)d_in[14];
    const float* as2 = (const float*)d_in[15];
    const float* ad2 = (const float*)d_in[16];
    const float* g2  = (const float*)d_in[18];
    const float* be2 = (const float*)d_in[19];
    const float* W3  = (const float*)d_in[20];
    const float* as3 = (const float*)d_in[21];
    const float* ad3 = (const float*)d_in[22];
    const float* g3  = (const float*)d_in[24];
    const float* be3 = (const float*)d_in[25];
    float* out = (float*)d_out;
    // GAT biases b1/bm/b2/b3 cancel inside the immediately-following BN (mean-subtract).

    char* ws = (char*)d_ws;
    size_t off = 0;
    auto alloc = [&](size_t b) {
        void* p = ws + off;
        off = (off + b + 255) & ~(size_t)255;
        return p;
    };
    int* rowptr = (int*)alloc((NN + 1) * 4);
    int* csr    = (int*)alloc((size_t)ET * 4);
    int* deg    = (int*)alloc(NN * 4);   // also reused as fill cursor
    int* tmp    = (int*)alloc(NN * 4);
    int* csum   = (int*)alloc(256 * 4);
    bf16* Hbf   = (bf16*)alloc((size_t)NN * 128 * 2);
    bf16* AG1   = (bf16*)alloc((size_t)NN * 128 * 2);
    bf16* AG2   = (bf16*)alloc((size_t)NN * 128 * 2);
    bf16* AG3   = (bf16*)alloc((size_t)NN * 64 * 2);
    bf16* AG4   = (bf16*)alloc((size_t)NN * 40 * 2);
    float* S    = (float*)alloc((size_t)NN * 8 * 4);
    float* Dv   = (float*)alloc((size_t)NN * 8 * 4);
    float* bns  = (float*)alloc(4 * 256 * 4);    // 4 BN-stat sets: [set][sum 128 | sq 128]
    float2* ss1 = (float2*)alloc(128 * 8);
    float2* ssM = (float2*)alloc(128 * 8);
    float2* ss2 = (float2*)alloc(64 * 8);
    short* WT1  = (short*)alloc(128 * 128 * 2);
    short* WTm  = (short*)alloc(128 * 128 * 2);
    short* WT2  = (short*)alloc(128 * 64 * 2);

    const int nchunks = (NN + 1023) / 1024;

    // ---- one upfront zero of all BN-stat sets
    hipMemsetAsync(bns, 0, 4 * 256 * 4, stream);
    // ---- weight transpose+convert (all in one)
    k_wconv_all<<<160, 256, 0, stream>>>(W1, Wm, W2, WT1, WTm, WT2);

    // ---- CSR build (rebuilt every call; ws is re-poisoned by harness)
    hipMemsetAsync(deg, 0, NN * 4, stream);
    k_hist<<<(ET + 255) / 256, 256, 0, stream>>>(ei, deg);
    k_scan_local<<<nchunks, 1024, 0, stream>>>(deg, tmp, csum);
    k_scan_chunks<<<1, 64, 0, stream>>>(csum, nchunks);
    k_rowptr<<<(NN + 255) / 256, 256, 0, stream>>>(tmp, csum, rowptr);
    hipMemsetAsync(deg, 0, NN * 4, stream);
    k_fill<<<(ET + 255) / 256, 256, 0, stream>>>(ei, rowptr, deg, csr);

    const int mfma_blocks = NN / 16;  // 3125, exact
    const int node_wave_blocks = (NN + 3) / 4; // 4 waves of 64 per 256-thread block

    // ---- Layer 1: IN=128 -> H=8 x C=16 (concat, D=128) -> AG1; BN stats + finalize
    k_gemm_mfma<128, 8, 0><<<mfma_blocks, 64, 0, stream>>>(x, nullptr, nullptr, nullptr, nullptr,
                                                           WT1, Hbf, as1, ad1, S, Dv);
    k_aggregate<8, 16, 128><<<node_wave_blocks, 256, 0, stream>>>(Hbf, S, Dv, rowptr, csr, AG1);
    k_bnstats<128><<<512, 128, 0, stream>>>(AG1, bns + 0 * 256);
    k_bnfin<128><<<1, 128, 0, stream>>>(bns + 0 * 256, g1, be1, ss1);

    // ---- Mid layer: input = elu(bn1(AG1)) fused into GEMM; H=1 scores fused -> AG2
    k_gemm_mfma<128, 1, 1><<<mfma_blocks, 64, 0, stream>>>(nullptr, AG1, ss1, nullptr, nullptr,
                                                           WTm, Hbf, asm_, adm, S, Dv);
    k_aggregate<1, 128, 128><<<node_wave_blocks, 256, 0, stream>>>(Hbf, S, Dv, rowptr, csr, AG2);
    k_bnstats<128><<<512, 128, 0, stream>>>(AG2, bns + 1 * 256);
    k_bnfin<128><<<1, 128, 0, stream>>>(bns + 1 * 256, gm, bem, ssM);

    // ---- Layer 2: input = elu(bnM(AG2)) + elu(bn1(AG1)) fused; H=4 -> AG3
    k_gemm_mfma<64, 4, 2><<<mfma_blocks, 64, 0, stream>>>(nullptr, AG2, ssM, AG1, ss1,
                                                          WT2, Hbf, as2, ad2, S, Dv);
    k_aggregate<4, 16, 64><<<node_wave_blocks, 256, 0, stream>>>(Hbf, S, Dv, rowptr, csr, AG3);
    k_bnstats<64><<<512, 64, 0, stream>>>(AG3, bns + 2 * 256);
    k_bnfin<64><<<1, 64, 0, stream>>>(bns + 2 * 256, g2, be2, ss2);

    // ---- Layer 3: input = elu(bn2(AG3)) fused into small GEMM; H=1 -> AG4; BN+log_softmax
    k_gemm_small<<<NN, 64, 0, stream>>>(AG3, ss2, W3, Hbf, as3, ad3, S, Dv);
    k_aggregate<1, 40, 40><<<node_wave_blocks, 256, 0, stream>>>(Hbf, S, Dv, rowptr, csr, AG4);
    k_bnstats<40><<<512, 64, 0, stream>>>(AG4, bns + 3 * 256);
    k_bn_logsoftmax<<<node_wave_blocks, 256, 0, stream>>>(AG4, bns + 3 * 256, g3, be3, out);
}

// Round 10
// 565.121 us; speedup vs baseline: 1.5156x; 1.0281x over previous
//
#include <hip/hip_runtime.h>
#include <hip/hip_bf16.h>
#include <math.h>

#define NN 50000
#define NE 600000
#define ET (NN + NE)        // 650000 edges incl. self-loops
#define FILLB ((ET + 255) / 256)   // 2540 blocks for hist/fill
#define NTILE (NN / 16)            // 3125 gemm tiles (exact)
#define GEMMB ((NTILE + 3) / 4)    // 782 blocks of 4 waves

typedef __hip_bfloat16 bf16;
typedef __attribute__((ext_vector_type(8))) short bf16x8;
typedef __attribute__((ext_vector_type(4))) float f32x4;

static __device__ inline unsigned short f2bf(float f) {
    union { __hip_bfloat16 h; unsigned short u; } v;
    v.h = __float2bfloat16(f);
    return v.u;
}
static __device__ inline float bf2f(bf16 h) { return __bfloat162float(h); }

// ---------------------------------------------------------------- hist + weight-convert (merged)
__global__ void k_hist_wconv(const int* __restrict__ ei, int* __restrict__ deg,
                             const float* __restrict__ W1, const float* __restrict__ Wm,
                             const float* __restrict__ W2, short* __restrict__ WT1,
                             short* __restrict__ WTm, short* __restrict__ WT2) {
    int b = blockIdx.x;
    if (b < FILLB) {
        int e = b * 256 + threadIdx.x;
        if (e < ET) {
            int d = (e < NE) ? ei[NE + e] : (e - NE);
            atomicAdd(&deg[d], 1);
        }
    } else {
        int idx = (b - FILLB) * 256 + threadIdx.x;
        if (idx < 16384) {                       // W1 [128][128] -> WT1 [128][128]
            int d = idx >> 7, k = idx & 127;
            WT1[idx] = (short)f2bf(W1[k * 128 + d]);
        } else if (idx < 32768) {                // Wm
            int i2 = idx - 16384;
            int d = i2 >> 7, k = i2 & 127;
            WTm[i2] = (short)f2bf(Wm[k * 128 + d]);
        } else if (idx < 40960) {                // W2 [128][64] -> WT2 [64][128]
            int i3 = idx - 32768;
            int d = i3 >> 7, k = i3 & 127;
            WT2[i3] = (short)f2bf(W2[k * 64 + d]);
        }
    }
}

// ---------------------------------------------------------------- degree scan (per-1024 chunk)
__global__ void k_scan_local(const int* __restrict__ deg, int* __restrict__ tmp,
                             int* __restrict__ csum) {
    __shared__ int wsum[16];
    int i = blockIdx.x * 1024 + threadIdx.x;
    int lane = threadIdx.x & 63, wid = threadIdx.x >> 6;
    int x = (i < NN) ? deg[i] : 0;
    for (int off = 1; off < 64; off <<= 1) {
        int y = __shfl_up(x, off);
        if (lane >= off) x += y;
    }
    if (lane == 63) wsum[wid] = x;
    __syncthreads();
    if (wid == 0) {
        int t = (lane < 16) ? wsum[lane] : 0;
        for (int off = 1; off < 16; off <<= 1) {
            int y = __shfl_up(t, off);
            if (lane >= off) t += y;
        }
        if (lane < 16) wsum[lane] = t;
    }
    __syncthreads();
    if (wid > 0) x += wsum[wid - 1];
    if (i < NN) tmp[i] = x;                        // inclusive within chunk
    if (threadIdx.x == 1023) csum[blockIdx.x] = x; // chunk total
}

// rowptr with inline chunk-prefix scan (nchunks=49 <= 64; redundant per block, trivial)
__global__ void k_rowptr(const int* __restrict__ tmp, const int* __restrict__ csum,
                         int* __restrict__ rowptr, int nchunks) {
    __shared__ int pref[64];
    if (threadIdx.x < 64) {
        int lane = threadIdx.x;
        int v = (lane < nchunks) ? csum[lane] : 0;
        for (int off = 1; off < 64; off <<= 1) {
            int y = __shfl_up(v, off);
            if (lane >= off) v += y;
        }
        pref[lane] = v;
    }
    __syncthreads();
    int i = blockIdx.x * blockDim.x + threadIdx.x;
    if (i == 0) rowptr[0] = 0;
    if (i < NN) {
        int chunk = i >> 10;
        int off = (chunk > 0) ? pref[chunk - 1] : 0;
        rowptr[i + 1] = tmp[i] + off;
    }
}

// ---------------------------------------------------------------- MFMA GEMM body (K=128)
// One wave per 16-row tile. MODE 0: fp32 input. MODE 1: bf16 + fused elu(bn).
// MODE 2: MODE 1 + fused residual elu(bn2(x2)). C/D: row=(lane>>4)*4+reg, col=lane&15.
template <int D, int HF, int MODE>
static __device__ __forceinline__ void gemm_body(int tile, int lane,
    const float* __restrict__ Xf, const bf16* __restrict__ X1, const float2* __restrict__ ss1,
    const bf16* __restrict__ X2, const float2* __restrict__ ss2,
    const short* __restrict__ WT, bf16* __restrict__ Hout,
    const float* __restrict__ a_s, const float* __restrict__ a_d,
    float* __restrict__ S, float* __restrict__ Dv) {
    constexpr int K = 128;
    constexpr int NT = D / 16;
    int rb = tile * 16;
    int m = lane & 15, kg = lane >> 4;

    f32x4 acc[NT];
#pragma unroll
    for (int n = 0; n < NT; n++) acc[n] = (f32x4){0.f, 0.f, 0.f, 0.f};

#pragma unroll
    for (int k0 = 0; k0 < K; k0 += 32) {
        int cb = k0 + kg * 8;
        bf16x8 a;
        if constexpr (MODE == 0) {
            const float* xp = Xf + (size_t)(rb + m) * K + cb;
            float4 f0 = *reinterpret_cast<const float4*>(xp);
            float4 f1 = *reinterpret_cast<const float4*>(xp + 4);
            a[0] = (short)f2bf(f0.x); a[1] = (short)f2bf(f0.y);
            a[2] = (short)f2bf(f0.z); a[3] = (short)f2bf(f0.w);
            a[4] = (short)f2bf(f1.x); a[5] = (short)f2bf(f1.y);
            a[6] = (short)f2bf(f1.z); a[7] = (short)f2bf(f1.w);
        } else {
            bf16x8 r1 = *reinterpret_cast<const bf16x8*>(X1 + (size_t)(rb + m) * K + cb);
            bf16x8 r2;
            if constexpr (MODE == 2)
                r2 = *reinterpret_cast<const bf16x8*>(X2 + (size_t)(rb + m) * K + cb);
#pragma unroll
            for (int j = 0; j < 8; j++) {
                float2 p1 = ss1[cb + j];
                bf16 b1; *(short*)&b1 = r1[j];
                float v = p1.x * bf2f(b1) + p1.y;
                v = (v > 0.f) ? v : (__expf(v) - 1.f);
                if constexpr (MODE == 2) {
                    float2 p2 = ss2[cb + j];
                    bf16 b2; *(short*)&b2 = r2[j];
                    float v2 = p2.x * bf2f(b2) + p2.y;
                    v2 = (v2 > 0.f) ? v2 : (__expf(v2) - 1.f);
                    v += v2;
                }
                a[j] = (short)f2bf(v);
            }
        }
#pragma unroll
        for (int n = 0; n < NT; n++) {
            bf16x8 b = *reinterpret_cast<const bf16x8*>(WT + (size_t)(n * 16 + m) * K + cb);
            acc[n] = __builtin_amdgcn_mfma_f32_16x16x32_bf16(a, b, acc[n], 0, 0, 0);
        }
    }

    float asv[NT], adv[NT];
#pragma unroll
    for (int n = 0; n < NT; n++) {
        asv[n] = a_s[n * 16 + m];
        adv[n] = a_d[n * 16 + m];
    }
#pragma unroll
    for (int r = 0; r < 4; r++) {
        int row = rb + kg * 4 + r;
#pragma unroll
        for (int n = 0; n < NT; n++)
            Hout[(size_t)row * D + n * 16 + m] = __float2bfloat16(acc[n][r]);
        if constexpr (HF == 1) {
            float sa = 0.f, da = 0.f;
#pragma unroll
            for (int n = 0; n < NT; n++) {
                sa += acc[n][r] * asv[n];
                da += acc[n][r] * adv[n];
            }
            for (int off = 1; off < 16; off <<= 1) {
                sa += __shfl_xor(sa, off);
                da += __shfl_xor(da, off);
            }
            if (m == 0) { S[row] = sa; Dv[row] = da; }
        } else {
            // C == 16: head index == col-tile index n
#pragma unroll
            for (int n = 0; n < NT; n++) {
                float sa = acc[n][r] * asv[n];
                float da = acc[n][r] * adv[n];
                for (int off = 1; off < 16; off <<= 1) {
                    sa += __shfl_xor(sa, off);
                    da += __shfl_xor(da, off);
                }
                if (m == 0) { S[row * HF + n] = sa; Dv[row * HF + n] = da; }
            }
        }
    }
}

template <int D, int HF, int MODE>
__global__ __launch_bounds__(64) void k_gemm_mfma(const float* Xf, const bf16* X1,
                                                  const float2* ss1, const bf16* X2,
                                                  const float2* ss2, const short* WT,
                                                  bf16* Hout, const float* a_s,
                                                  const float* a_d, float* S, float* Dv) {
    gemm_body<D, HF, MODE>(blockIdx.x, threadIdx.x, Xf, X1, ss1, X2, ss2, WT, Hout, a_s, a_d, S, Dv);
}

// ---------------------------------------------------------------- CSR fill + layer-1 GEMM (merged)
__global__ __launch_bounds__(256) void k_fill_gemm1(const int* __restrict__ ei,
                                                    const int* __restrict__ rowptr,
                                                    int* __restrict__ fill, int* __restrict__ csr,
                                                    const float* __restrict__ x,
                                                    const short* __restrict__ WT1,
                                                    bf16* __restrict__ Hout,
                                                    const float* __restrict__ as1,
                                                    const float* __restrict__ ad1,
                                                    float* __restrict__ S, float* __restrict__ Dv) {
    if (blockIdx.x < FILLB) {
        int e = blockIdx.x * 256 + threadIdx.x;
        if (e >= ET) return;
        int s = (e < NE) ? ei[e] : (e - NE);
        int d = (e < NE) ? ei[NE + e] : (e - NE);
        int pos = atomicAdd(&fill[d], 1);
        csr[rowptr[d] + pos] = s;
        return;
    }
    int tile = (blockIdx.x - FILLB) * 4 + (threadIdx.x >> 6);
    if (tile >= NTILE) return;
    gemm_body<128, 8, 0>(tile, threadIdx.x & 63, x, nullptr, nullptr, nullptr, nullptr,
                         WT1, Hout, as1, ad1, S, Dv);
}

// K=64, D=40 (layer 3): one node per 64-thread block; fused elu(bn(x)) input + H=1 scores.
__global__ void k_gemm_small(const bf16* __restrict__ X, const float2* __restrict__ ss,
                             const float* __restrict__ W, bf16* __restrict__ Hout,
                             const float* __restrict__ a_s, const float* __restrict__ a_d,
                             float* __restrict__ S, float* __restrict__ Dv) {
    __shared__ float xs[64];
    int n = blockIdx.x, t = threadIdx.x;
    {
        float2 p = ss[t];
        float v = p.x * bf2f(X[n * 64 + t]) + p.y;
        xs[t] = (v > 0.f) ? v : (__expf(v) - 1.f);
    }
    __syncthreads();
    float acc = 0.f;
    if (t < 40) {
#pragma unroll
        for (int k = 0; k < 64; k++) acc += xs[k] * W[k * 40 + t];
        Hout[n * 40 + t] = __float2bfloat16(acc);
    }
    float sa = (t < 40) ? acc * a_s[t] : 0.f;
    float da = (t < 40) ? acc * a_d[t] : 0.f;
    for (int off = 32; off; off >>= 1) {
        sa += __shfl_xor(sa, off);
        da += __shfl_xor(da, off);
    }
    if (t == 0) {
        S[n] = sa;
        Dv[n] = da;
    }
}

// ---------------------------------------------------------------- aggregation (one-pass)
// out = sum_e w_e * h_e / sum_e w_e  with w = exp(leaky(S[src]+Dv[dst])) — the
// denominator is accumulated ALONGSIDE the weighted sum (no phase-1, no LDS).
// Lane j owns column pair (2j,2j+1); head is lane-constant. 4-way unrolled
// (8-way regressed in R8: VGPR 32->44, occ 63->42%). bf16 packed output.
template <int H, int C, int D>
__global__ __launch_bounds__(256) void k_aggregate(const bf16* __restrict__ Hb,
                                                   const float* __restrict__ S,
                                                   const float* __restrict__ Dv,
                                                   const int* __restrict__ rowptr,
                                                   const int* __restrict__ csr,
                                                   bf16* __restrict__ Out) {
    int node = blockIdx.x * 4 + (threadIdx.x >> 6);
    if (node >= NN) return;
    int lane = threadIdx.x & 63;
    int r0 = rowptr[node], r1 = rowptr[node + 1];
    int cnt = r1 - r0;
    constexpr int EPI = (D > 64) ? 1 : 2;  // edges per iteration
    constexpr int LP = 64 / EPI;           // lanes per edge
    int sub = lane / LP;
    int j = lane % LP;                     // column pair (2j, 2j+1)
    bool act = (2 * j) < D;
    const int h_l = act ? (2 * j) / C : 0; // lane-constant head
    float dn_l = Dv[node * H + h_l];

    float ax = 0.f, ay = 0.f, den = 0.f;
    int k = sub;
    for (; k + 3 * EPI < cnt; k += 4 * EPI) {
        int uu[4];
        float svv[4];
        unsigned pp[4];
#pragma unroll
        for (int i = 0; i < 4; i++) uu[i] = csr[r0 + k + i * EPI];
#pragma unroll
        for (int i = 0; i < 4; i++) svv[i] = S[(size_t)uu[i] * H + h_l];
#pragma unroll
        for (int i = 0; i < 4; i++)
            pp[i] = act ? *reinterpret_cast<const unsigned*>(Hb + (size_t)uu[i] * D + 2 * j) : 0u;
#pragma unroll
        for (int i = 0; i < 4; i++) {
            float e = svv[i] + dn_l;
            e = fmaxf(e, 0.2f * e);        // leaky_relu
            float w = __expf(e);
            den += w;
            ax += w * __uint_as_float(pp[i] << 16);
            ay += w * __uint_as_float(pp[i] & 0xffff0000u);
        }
    }
    for (; k < cnt; k += EPI) {
        int u = csr[r0 + k];
        float e = S[(size_t)u * H + h_l] + dn_l;
        e = fmaxf(e, 0.2f * e);
        float w = __expf(e);
        den += w;
        unsigned pv = act ? *reinterpret_cast<const unsigned*>(Hb + (size_t)u * D + 2 * j) : 0u;
        ax += w * __uint_as_float(pv << 16);
        ay += w * __uint_as_float(pv & 0xffff0000u);
    }
    if (EPI == 2) {
        ax += __shfl_xor(ax, 32);
        ay += __shfl_xor(ay, 32);
        den += __shfl_xor(den, 32);
    }
    if (act && lane < LP) {
        float inv = 1.f / (den + 1e-16f);
        unsigned o = (unsigned)f2bf(ax * inv) | ((unsigned)f2bf(ay * inv) << 16);
        *reinterpret_cast<unsigned*>(Out + (size_t)node * D + 2 * j) = o;
    }
}

// ---------------------------------------------------------------- batchnorm stats (+ fused finalize)
// FIN: last block (atomic counter) computes per-column (scale, shift). Coherent
// re-read of sums via atomicAdd(p, 0) — per-XCD L2s are not cross-coherent.
template <int D, bool FIN>
__global__ void k_bnstats(const bf16* __restrict__ X, float* __restrict__ sums,
                          int* __restrict__ cnt, const float* __restrict__ g,
                          const float* __restrict__ be, float2* __restrict__ ss) {
    int col = threadIdx.x;
    if (col < D) {
        float s = 0.f, q = 0.f;
        for (int r = blockIdx.x; r < NN; r += gridDim.x) {
            float v = bf2f(X[(size_t)r * D + col]);
            s += v;
            q += v * v;
        }
        atomicAdd(&sums[col], s);
        atomicAdd(&sums[128 + col], q);
    }
    if constexpr (FIN) {
        __shared__ int lastFlag;
        __threadfence();
        __syncthreads();
        if (threadIdx.x == 0)
            lastFlag = (atomicAdd(cnt, 1) == (int)gridDim.x - 1) ? 1 : 0;
        __syncthreads();
        if (lastFlag && col < D) {
            float su = atomicAdd(&sums[col], 0.f);
            float sq = atomicAdd(&sums[128 + col], 0.f);
            float mu = su * (1.f / NN);
            float var = sq * (1.f / NN) - mu * mu;
            float sc = g[col] * rsqrtf(var + 1e-5f);
            ss[col] = make_float2(sc, be[col] - mu * sc);
        }
    }
}

// Layer 3: fused BN + log_softmax over 40 classes; one wave per node. bf16 in, fp32 out.
__global__ void k_bn_logsoftmax(const bf16* __restrict__ X, const float* __restrict__ sums,
                                const float* __restrict__ g, const float* __restrict__ be,
                                float* __restrict__ Out) {
    int node = (blockIdx.x * blockDim.x + threadIdx.x) >> 6;
    int lane = threadIdx.x & 63;
    if (node >= NN) return;
    float bnv = 0.f, v = -1e30f;
    if (lane < 40) {
        float mu = sums[lane] * (1.f / NN);
        float var = sums[128 + lane] * (1.f / NN) - mu * mu;
        float sc = g[lane] * rsqrtf(var + 1e-5f);
        bnv = sc * (bf2f(X[node * 40 + lane]) - mu) + be[lane];
        v = bnv;
    }
    float m = v;
    for (int off = 32; off; off >>= 1) m = fmaxf(m, __shfl_xor(m, off));
    float ex = (lane < 40) ? expf(bnv - m) : 0.f;
    for (int off = 32; off; off >>= 1) ex += __shfl_xor(ex, off);
    float lse = m + logf(ex);
    if (lane < 40) Out[node * 40 + lane] = bnv - lse;
}

// ---------------------------------------------------------------- launch (17 dispatches)
extern "C" void kernel_launch(void* const* d_in, const int* in_sizes, int n_in,
                              void* d_out, int out_size, void* d_ws, size_t ws_size,
                              hipStream_t stream) {
    (void)in_sizes; (void)n_in; (void)out_size; (void)ws_size;
    const float* x   = (const float*)d_in[0];
    const int*   ei  = (const int*)d_in[1];
    const float* W1  = (const float*)d_in[2];
    const float* as1 = (const float*)d_in[3];
    const float* ad1 = (const float*)d_in[4];
    const float* g1  = (const float*)d_in[6];
    const float* be1 = (const float*)d_in[7];
    const float* Wm  = (const float*)d_in[8];
    const float* asm_ = (const float*)d_in[9];
    const float* adm = (const float*)d_in[10];
    const float* gm  = (const float*)d_in[12];
    const float* bem = (const float*)d_in[13];
    const float* W2  = (const float*)d_in[14];
    const float* as2 = (const float*)d_in[15];
    const float* ad2 = (const float*)d_in[16];
    const float* g2  = (const float*)d_in[18];
    const float* be2 = (const float*)d_in[19];
    const float* W3  = (const float*)d_in[20];
    const float* as3 = (const float*)d_in[21];
    const float* ad3 = (const float*)d_in[22];
    const float* g3  = (const float*)d_in[24];
    const float* be3 = (const float*)d_in[25];
    float* out = (float*)d_out;
    // GAT biases b1/bm/b2/b3 cancel inside the immediately-following BN (mean-subtract).

    char* ws = (char*)d_ws;
    size_t off = 0;
    auto alloc = [&](size_t b) {
        void* p = ws + off;
        off = (off + b + 255) & ~(size_t)255;
        return p;
    };
    int* rowptr = (int*)alloc((NN + 1) * 4);
    int* csr    = (int*)alloc((size_t)ET * 4);
    // single zeroed region: deg | fill | bns(4x256 f32) | cnt(4 i32)
    const size_t ZB = (size_t)NN * 4 + (size_t)NN * 4 + 1024 * 4 + 16;
    char* zb    = (char*)alloc(ZB);
    int* deg    = (int*)zb;
    int* fillc  = (int*)(zb + (size_t)NN * 4);
    float* bns  = (float*)(zb + 2 * (size_t)NN * 4);
    int* cnt    = (int*)(zb + 2 * (size_t)NN * 4 + 1024 * 4);
    int* tmp    = (int*)alloc(NN * 4);
    int* csum   = (int*)alloc(256 * 4);
    bf16* Hbf   = (bf16*)alloc((size_t)NN * 128 * 2);
    bf16* AG1   = (bf16*)alloc((size_t)NN * 128 * 2);
    bf16* AG2   = (bf16*)alloc((size_t)NN * 128 * 2);
    bf16* AG3   = (bf16*)alloc((size_t)NN * 64 * 2);
    bf16* AG4   = (bf16*)alloc((size_t)NN * 40 * 2);
    float* S    = (float*)alloc((size_t)NN * 8 * 4);
    float* Dv   = (float*)alloc((size_t)NN * 8 * 4);
    float2* ss1 = (float2*)alloc(128 * 8);
    float2* ssM = (float2*)alloc(128 * 8);
    float2* ss2 = (float2*)alloc(64 * 8);
    short* WT1  = (short*)alloc(128 * 128 * 2);
    short* WTm  = (short*)alloc(128 * 128 * 2);
    short* WT2  = (short*)alloc(128 * 64 * 2);

    const int nchunks = (NN + 1023) / 1024;  // 49
    const int node_wave_blocks = (NN + 3) / 4;

    // 1. one memset for all zeroed state
    hipMemsetAsync(zb, 0, ZB, stream);
    // 2. degree histogram + weight transpose/convert
    k_hist_wconv<<<FILLB + 160, 256, 0, stream>>>(ei, deg, W1, Wm, W2, WT1, WTm, WT2);
    // 3-4. prefix scan -> rowptr (chunk scan inlined)
    k_scan_local<<<nchunks, 1024, 0, stream>>>(deg, tmp, csum);
    k_rowptr<<<(NN + 255) / 256, 256, 0, stream>>>(tmp, csum, rowptr, nchunks);
    // 5. CSR fill + layer-1 GEMM (independent work, one dispatch)
    k_fill_gemm1<<<FILLB + GEMMB, 256, 0, stream>>>(ei, rowptr, fillc, csr, x, WT1, Hbf, as1, ad1, S, Dv);
    // 6-7. layer 1 aggregate; BN stats+finalize
    k_aggregate<8, 16, 128><<<node_wave_blocks, 256, 0, stream>>>(Hbf, S, Dv, rowptr, csr, AG1);
    k_bnstats<128, true><<<512, 128, 0, stream>>>(AG1, bns + 0 * 256, cnt + 0, g1, be1, ss1);
    // 8-10. mid layer (input = elu(bn1(AG1)) fused; H=1 scores fused)
    k_gemm_mfma<128, 1, 1><<<NTILE, 64, 0, stream>>>(nullptr, AG1, ss1, nullptr, nullptr, WTm,
                                                     Hbf, asm_, adm, S, Dv);
    k_aggregate<1, 128, 128><<<node_wave_blocks, 256, 0, stream>>>(Hbf, S, Dv, rowptr, csr, AG2);
    k_bnstats<128, true><<<512, 128, 0, stream>>>(AG2, bns + 1 * 256, cnt + 1, gm, bem, ssM);
    // 11-13. layer 2 (input = elu(bnM(AG2)) + elu(bn1(AG1)) fused)
    k_gemm_mfma<64, 4, 2><<<NTILE, 64, 0, stream>>>(nullptr, AG2, ssM, AG1, ss1, WT2,
                                                    Hbf, as2, ad2, S, Dv);
    k_aggregate<4, 16, 64><<<node_wave_blocks, 256, 0, stream>>>(Hbf, S, Dv, rowptr, csr, AG3);
    k_bnstats<64, true><<<512, 64, 0, stream>>>(AG3, bns + 2 * 256, cnt + 2, g2, be2, ss2);
    // 14-17. layer 3 (input = elu(bn2(AG3)) fused into small GEMM); BN + log_softmax
    k_gemm_small<<<NN, 64, 0, stream>>>(AG3, ss2, W3, Hbf, as3, ad3, S, Dv);
    k_aggregate<1, 40, 40><<<node_wave_blocks, 256, 0, stream>>>(Hbf, S, Dv, rowptr, csr, AG4);
    k_bnstats<40, false><<<512, 64, 0, stream>>>(AG4, bns + 3 * 256, nullptr, nullptr, nullptr, nullptr);
    k_bn_logsoftmax<<<node_wave_blocks, 256, 0, stream>>>(AG4, bns + 3 * 256, g3, be3, out);
}